// Round 4
// baseline (348.949 us; speedup 1.0000x reference)
//
#include <hip/hip_runtime.h>
#include <hip/hip_bf16.h>

#define NNODES 4096
#define NEDGES 131072
#define D_IN   768
#define D_H    256
#define NHEAD  4
#define D_HEAD 64
#define D_OUT  128

// ---------------- workspace layout (bytes) ----------------
#define OFF_H0     (0u)
#define OFF_H1     (4u<<20)
#define OFF_HH     (8u<<20)
#define OFF_WCAT   (12u<<20)                    // 256*256*4 = 262144
#define OFF_SSRC   (OFF_WCAT + 262144u)         // 4096*4*4 = 65536
#define OFF_SDST   (OFF_SSRC + 65536u)          // 65536
#define OFF_ROWPTR (OFF_SDST + 65536u)          // 4097*4 -> pad 16640
#define OFF_CSR    (OFF_ROWPTR + 16640u)        // 131072*4 = 524288
#define OFF_ROWS   (OFF_CSR + 524288u)          // 524288
#define OFF_COLS   (OFF_ROWS + 524288u)         // 524288
#define OFF_FLAG   (OFF_COLS + 524288u)         // 256
#define OFF_S      (OFF_FLAG + 256u)            // 1024 (memset per layer)
#define OFF_ZERO   (OFF_S + 1024u)              // zeroed-once region
#define OFF_DEG    (OFF_ZERO)                   // 16384
#define OFF_DCNT   (OFF_DEG + 16384u)           // 16384
#define OFF_BITMAP (OFF_DCNT + 16384u)          // 4096*4096/8 = 2097152
#define ZERO_BYTES (16384u + 16384u + 2097152u)

// ---------------- edge dtype autodetect ----------------
// int64-pushed edges have all-zero high int32 words (values < 4096); genuine
// int32 edges have random node ids in odd slots -> P(all 64 zero) ~ 4096^-64.
__global__ void edge_detect(const int* __restrict__ ei, int* __restrict__ flag)
{
    int t = threadIdx.x;                 // 64 threads, one wave
    int v = ei[2*t + 1];
    unsigned long long ball = __ballot(v == 0);
    if (t == 0) flag[0] = (ball == ~0ull) ? 1 : 0;
}

__global__ void edge_norm(const int* __restrict__ ei, const int* __restrict__ flag,
                          int* __restrict__ rows, int* __restrict__ cols)
{
    int k = blockIdx.x*256 + threadIdx.x;
    if (k >= NEDGES) return;
    int is64 = flag[0];
    int r = is64 ? ei[2*k]            : ei[k];
    int c = is64 ? ei[2*NEDGES + 2*k] : ei[NEDGES + k];
    rows[k] = r & (NNODES-1);
    cols[k] = c & (NNODES-1);
}

// ---------------- GEMM: C = act(A@B + bias), all f32 ----------------
// A: MxK row-major, B: KxN row-major. 64x64 tile, BK=16, 256 thr, 4x4 micro.
// relu: 0 = none, 1 = relu
__global__ __launch_bounds__(256) void gemm_bias_act(
    const float* __restrict__ A, const float* __restrict__ B,
    const float* __restrict__ bias, float* __restrict__ C,
    int M, int N, int K, int relu)
{
    __shared__ float As[16][68];
    __shared__ float Bs[16][68];
    const int tid = threadIdx.x;
    const int bx = blockIdx.x;   // N tile
    const int by = blockIdx.y;   // M tile
    const int tx = tid & 15, ty = tid >> 4;
    float acc[4][4] = {};
    for (int k0 = 0; k0 < K; k0 += 16) {
        {   // A tile: 64 rows x 16 k
            int r  = tid >> 2;
            int kk = (tid & 3) * 4;
            float4 v = *(const float4*)&A[(size_t)(by*64 + r)*K + k0 + kk];
            As[kk+0][r] = v.x; As[kk+1][r] = v.y; As[kk+2][r] = v.z; As[kk+3][r] = v.w;
        }
        {   // B tile: 16 k x 64 cols
            int kk = tid >> 4;
            int c  = (tid & 15) * 4;
            float4 v = *(const float4*)&B[(size_t)(k0+kk)*N + bx*64 + c];
            Bs[kk][c+0] = v.x; Bs[kk][c+1] = v.y; Bs[kk][c+2] = v.z; Bs[kk][c+3] = v.w;
        }
        __syncthreads();
        #pragma unroll
        for (int k = 0; k < 16; ++k) {
            float4 av = *(const float4*)&As[k][ty*4];
            float4 bv = *(const float4*)&Bs[k][tx*4];
            float a4[4] = {av.x, av.y, av.z, av.w};
            float b4[4] = {bv.x, bv.y, bv.z, bv.w};
            #pragma unroll
            for (int i = 0; i < 4; ++i)
                #pragma unroll
                for (int j = 0; j < 4; ++j)
                    acc[i][j] = fmaf(a4[i], b4[j], acc[i][j]);
        }
        __syncthreads();
    }
    #pragma unroll
    for (int i = 0; i < 4; ++i) {
        int r = by*64 + ty*4 + i;
        #pragma unroll
        for (int j = 0; j < 4; ++j) {
            int c = bx*64 + tx*4 + j;
            float v = acc[i][j] + (bias ? bias[c] : 0.f);
            if (relu) v = fmaxf(v, 0.f);
            C[(size_t)r*N + c] = v;
        }
    }
}

// ---------------- repack Wg[l] (H,D_H,D_HEAD) -> (D_H, H*D_HEAD) ----------------
__global__ void wcat_kernel(const float* __restrict__ Wg, int l, float* __restrict__ wcat)
{
    int idx = blockIdx.x*256 + threadIdx.x;      // 65536
    int i = idx >> 8, j = idx & 255;
    int h = j >> 6, o = j & 63;
    wcat[idx] = Wg[((l*NHEAD + h)*D_H + i)*D_HEAD + o];
}

// ---------------- column sums of hh (4096x256) -> S[256] ----------------
__global__ void colsum_kernel(const float* __restrict__ hh, float* __restrict__ S)
{
    int j = threadIdx.x;          // 256 cols
    int b = blockIdx.x;           // 16 blocks of 256 rows
    float s = 0.f;
    for (int r = b*256; r < (b+1)*256; ++r) s += hh[(size_t)r*256 + j];
    atomicAdd(&S[j], s);
}

// ---------------- per-node attention scores ----------------
// one wave per node: ssrc[n*4+h] = <hh[n,h,:], a_src[h,:]>, sdst likewise
__global__ __launch_bounds__(256) void score_kernel(
    const float* __restrict__ hh, const float* __restrict__ a_l,
    float* __restrict__ ssrc, float* __restrict__ sdst)
{
    int wid  = (blockIdx.x * 256 + threadIdx.x) >> 6;
    int lane = threadIdx.x & 63;
    if (wid >= NNODES) return;
    int n = wid;
    #pragma unroll
    for (int h = 0; h < NHEAD; ++h) {
        float x  = hh[(size_t)n*256 + h*64 + lane];
        float vs = x * a_l[h*128 + lane];
        float vd = x * a_l[h*128 + 64 + lane];
        #pragma unroll
        for (int off = 32; off; off >>= 1) {
            vs += __shfl_down(vs, off);
            vd += __shfl_down(vd, off);
        }
        if (lane == 0) { ssrc[n*4 + h] = vs; sdst[n*4 + h] = vd; }
    }
}

// ---------------- CSR build (once; edges are layer-invariant) ----------------
__global__ void hist_kernel(const int* __restrict__ rows, int* __restrict__ deg)
{
    int k = blockIdx.x*256 + threadIdx.x;
    if (k < NEDGES) atomicAdd(&deg[rows[k]], 1);
}

__global__ __launch_bounds__(1024) void exscan_kernel(
    const int* __restrict__ deg, int* __restrict__ rowptr)
{
    __shared__ int buf[1024];
    int tid = threadIdx.x;
    int base = tid*4;
    int d0 = deg[base], d1 = deg[base+1], d2 = deg[base+2], d3 = deg[base+3];
    int tot = d0+d1+d2+d3;
    buf[tid] = tot;
    __syncthreads();
    for (int off = 1; off < 1024; off <<= 1) {
        int x = 0;
        if (tid >= off) x = buf[tid - off];
        __syncthreads();
        buf[tid] += x;
        __syncthreads();
    }
    int excl = buf[tid] - tot;
    rowptr[base+0] = excl;
    rowptr[base+1] = excl + d0;
    rowptr[base+2] = excl + d0 + d1;
    rowptr[base+3] = excl + d0 + d1 + d2;
    if (tid == 1023) rowptr[4096] = buf[1023];
}

// dedup via bitmap: exactly one scatter per distinct (row,col); duplicates
// carry identical scores so any-winner is value-deterministic.
__global__ void scatter_kernel(const int* __restrict__ rows, const int* __restrict__ cols,
                               unsigned* __restrict__ bitmap,
                               const int* __restrict__ rowptr,
                               int* __restrict__ dcnt,
                               int* __restrict__ csr_col)
{
    int k = blockIdx.x*256 + threadIdx.x;
    if (k >= NEDGES) return;
    int n = rows[k], m = cols[k];
    unsigned bit = (unsigned)n*4096u + (unsigned)m;
    unsigned msk = 1u << (bit & 31);
    unsigned old = atomicOr(&bitmap[bit >> 5], msk);
    if (old & msk) return;
    int pos = rowptr[n] + atomicAdd(&dcnt[n], 1);
    csr_col[pos] = m;
}

// ---------------- per-node aggregation + dense-softmax + relu ----------------
// Exact identity for softmax over a row that is 0 at non-edges:
//   M = max(0, max_e e); base = exp(-M)
//   Z = sum_edges(exp(e-M)-base) + N*base
//   hp = [ sum_edges (exp(e-M)-base)*hh[m] + base*S ] / Z
// block = node; wave (tid>>6) = head; lane = output channel
__global__ __launch_bounds__(256) void aggregate_kernel(
    const int* __restrict__ rowptr, const int* __restrict__ dcnt,
    const int* __restrict__ csr_col,
    const float* __restrict__ ssrc, const float* __restrict__ sdst,
    const float* __restrict__ hh, const float* __restrict__ S,
    float* __restrict__ hout)
{
    int n = blockIdx.x;
    int h = threadIdx.x >> 6, o = threadIdx.x & 63;
    int start = rowptr[n], cnt = dcnt[n];
    float ss = ssrc[n*4 + h];

    // pass 1: row max (edges strided across lanes); baseline 0 from non-edges
    float mx = 0.f;
    for (int i = o; i < cnt; i += 64) {
        int m = csr_col[start + i];
        float e = ss + sdst[m*4 + h];
        e = (e >= 0.f) ? e : 0.2f*e;
        mx = fmaxf(mx, e);
    }
    #pragma unroll
    for (int off = 32; off; off >>= 1) mx = fmaxf(mx, __shfl_xor(mx, off));
    float M = mx;
    float base = expf(-M);

    // pass 2: weighted accumulate (lanes iterate edges together; lane owns o)
    float zsum = 0.f, acc = 0.f;
    for (int i = 0; i < cnt; ++i) {
        int m = csr_col[start + i];
        float e = ss + sdst[m*4 + h];
        e = (e >= 0.f) ? e : 0.2f*e;
        float c = expf(e - M) - base;
        zsum += c;
        acc += c * hh[(size_t)m*256 + h*64 + o];
    }
    float Z  = zsum + (float)NNODES * base;
    float hp = (acc + base * S[h*64 + o]) / Z;
    hout[(size_t)n*256 + h*64 + o] = fmaxf(hp, 0.f);
}

// ---------------- host: size-based input resolution ----------------
static int find_size(const int* sz, int n, int want, int fallback)
{
    for (int i = 0; i < n; ++i) if (sz[i] == want) return i;
    return fallback;
}

extern "C" void kernel_launch(void* const* d_in, const int* in_sizes, int n_in,
                              void* d_out, int out_size, void* d_ws, size_t ws_size,
                              hipStream_t stream)
{
    // identify inputs by flat element count (all 8 are distinct); fall back
    // to setup_inputs() dict order if a size is missing.
    int ix   = find_size(in_sizes, n_in, NNODES*D_IN, 0);          // 3145728
    int ie   = find_size(in_sizes, n_in, 2*NEDGES, 1);             // 262144
    if (in_sizes[ie] != 2*NEDGES) ie = find_size(in_sizes, n_in, 4*NEDGES, 1);
    int iwin = find_size(in_sizes, n_in, D_IN*D_H, 2);             // 196608
    int ibin = find_size(in_sizes, n_in, D_H, 3);                  // 256
    int iwg  = find_size(in_sizes, n_in, 2*NHEAD*D_H*D_HEAD, 4);   // 131072
    int ia   = find_size(in_sizes, n_in, 2*NHEAD*2*D_HEAD, 5);     // 1024
    int iwo  = find_size(in_sizes, n_in, D_H*D_OUT, 6);            // 32768
    int ibo  = find_size(in_sizes, n_in, D_OUT, 7);                // 128

    const float* x    = (const float*)d_in[ix];
    const int*   ei   = (const int*)d_in[ie];
    const float* Win  = (const float*)d_in[iwin];
    const float* bin_ = (const float*)d_in[ibin];
    const float* Wg   = (const float*)d_in[iwg];
    const float* a    = (const float*)d_in[ia];
    const float* Wout = (const float*)d_in[iwo];
    const float* bout = (const float*)d_in[ibo];
    float* out = (float*)d_out;                    // reference output is f32

    char* ws = (char*)d_ws;
    float* h0     = (float*)(ws + OFF_H0);
    float* h1     = (float*)(ws + OFF_H1);
    float* hh     = (float*)(ws + OFF_HH);
    float* wcat   = (float*)(ws + OFF_WCAT);
    float* ssrc   = (float*)(ws + OFF_SSRC);
    float* sdst   = (float*)(ws + OFF_SDST);
    int*   rowptr = (int*)(ws + OFF_ROWPTR);
    int*   csr    = (int*)(ws + OFF_CSR);
    int*   rows   = (int*)(ws + OFF_ROWS);
    int*   cols   = (int*)(ws + OFF_COLS);
    int*   flag   = (int*)(ws + OFF_FLAG);
    float* S      = (float*)(ws + OFF_S);
    int*   deg    = (int*)(ws + OFF_DEG);
    int*   dcnt   = (int*)(ws + OFF_DCNT);
    unsigned* bitmap = (unsigned*)(ws + OFF_BITMAP);

    // ---- edge normalization + CSR build, once (layer-invariant) ----
    edge_detect<<<1, 64, 0, stream>>>(ei, flag);
    edge_norm<<<NEDGES/256, 256, 0, stream>>>(ei, flag, rows, cols);
    hipMemsetAsync(ws + OFF_ZERO, 0, ZERO_BYTES, stream);   // deg, dcnt, bitmap
    hist_kernel<<<NEDGES/256, 256, 0, stream>>>(rows, deg);
    exscan_kernel<<<1, 1024, 0, stream>>>(deg, rowptr);
    scatter_kernel<<<NEDGES/256, 256, 0, stream>>>(rows, cols, bitmap, rowptr, dcnt, csr);

    // ---- input projection: h0 = relu(x @ Win + bin) ----
    {
        dim3 g(D_H/64, NNODES/64);
        gemm_bias_act<<<g, 256, 0, stream>>>(x, Win, bin_, h0, NNODES, D_H, D_IN, 1);
    }

    float* hin = h0;
    float* hcur = h1;
    for (int l = 0; l < 2; ++l) {
        hipMemsetAsync(ws + OFF_S, 0, 1024, stream);        // S only

        wcat_kernel<<<256, 256, 0, stream>>>(Wg, l, wcat);

        dim3 g2(D_H/64, NNODES/64);
        gemm_bias_act<<<g2, 256, 0, stream>>>(hin, wcat, nullptr, hh, NNODES, D_H, D_H, 0);

        colsum_kernel<<<16, 256, 0, stream>>>(hh, S);
        score_kernel<<<NNODES/4, 256, 0, stream>>>(hh, a + (size_t)l*NHEAD*128,
                                                   ssrc, sdst);
        aggregate_kernel<<<NNODES, 256, 0, stream>>>(rowptr, dcnt, csr,
                                                     ssrc, sdst, hh, S, hcur);
        float* t = hin; hin = hcur; hcur = t;
    }

    // ---- output projection -> f32 ----
    {
        dim3 g(D_OUT/64, NNODES/64);
        gemm_bias_act<<<g, 256, 0, stream>>>(hin, Wout, bout, out, NNODES, D_OUT, D_H, 0);
    }
}

// Round 5
// 213.472 us; speedup vs baseline: 1.6346x; 1.6346x over previous
//
#include <hip/hip_runtime.h>
#include <hip/hip_bf16.h>

#define NNODES 4096
#define NEDGES 131072
#define D_IN   768
#define D_H    256
#define NHEAD  4
#define D_HEAD 64
#define D_OUT  128

// ---------------- workspace layout (bytes) ----------------
#define OFF_H0     (0u)
#define OFF_H1     (4u<<20)
#define OFF_HH     (8u<<20)
#define OFF_SPART  (12u<<20)                    // 256*256*4 = 262144
#define OFF_SSRC   (OFF_SPART + 262144u)        // 4096*4*4 = 65536
#define OFF_SDST   (OFF_SSRC + 65536u)          // 65536
#define OFF_ROWPTR (OFF_SDST + 65536u)          // 4097*4 -> pad 16640
#define OFF_CSR    (OFF_ROWPTR + 16640u)        // 131072*4 = 524288
#define OFF_ROWS   (OFF_CSR + 524288u)          // 524288
#define OFF_COLS   (OFF_ROWS + 524288u)         // 524288
#define OFF_FLAG   (OFF_COLS + 524288u)         // 256
#define OFF_S      (OFF_FLAG + 256u)            // 1024
#define OFF_ZERO   (OFF_S + 1024u)              // zeroed-once region
#define OFF_DEG    (OFF_ZERO)                   // 16384
#define OFF_DCNT   (OFF_DEG + 16384u)           // 16384
#define OFF_BITMAP (OFF_DCNT + 16384u)          // 4096*4096/8 = 2097152
#define ZERO_BYTES (16384u + 16384u + 2097152u)

// ---------------- edge dtype autodetect ----------------
__global__ void edge_detect(const int* __restrict__ ei, int* __restrict__ flag)
{
    int t = threadIdx.x;                 // 64 threads, one wave
    int v = ei[2*t + 1];
    unsigned long long ball = __ballot(v == 0);
    if (t == 0) flag[0] = (ball == ~0ull) ? 1 : 0;
}

// normalize edges + histogram degrees (deg must be pre-zeroed)
__global__ void edge_norm(const int* __restrict__ ei, const int* __restrict__ flag,
                          int* __restrict__ rows, int* __restrict__ cols,
                          int* __restrict__ deg)
{
    int k = blockIdx.x*256 + threadIdx.x;
    if (k >= NEDGES) return;
    int is64 = flag[0];
    int r = is64 ? ei[2*k]            : ei[k];
    int c = is64 ? ei[2*NEDGES + 2*k] : ei[NEDGES + k];
    r &= (NNODES-1); c &= (NNODES-1);
    rows[k] = r;
    cols[k] = c;
    atomicAdd(&deg[r], 1);
}

// ---------------- GEMM: C = act(A@B + bias), all f32 ----------------
// A: MxK row-major. Normal mode: B is KxN row-major.
// wgB mode (hh GEMM): B points at Wg[l] with layout (H, D_H, D_HEAD) and
// logical column c = h*64+o maps to Wg[h][k][o]; a 64-wide N-tile is exactly
// one head (D_HEAD=64), so head = bx.
__global__ __launch_bounds__(256) void gemm_bias_act(
    const float* __restrict__ A, const float* __restrict__ B,
    const float* __restrict__ bias, float* __restrict__ C,
    int M, int N, int K, int relu, int wgB)
{
    __shared__ float As[16][68];
    __shared__ float Bs[16][68];
    const int tid = threadIdx.x;
    const int bx = blockIdx.x;   // N tile
    const int by = blockIdx.y;   // M tile
    const int tx = tid & 15, ty = tid >> 4;
    float acc[4][4] = {};
    for (int k0 = 0; k0 < K; k0 += 16) {
        {   // A tile: 64 rows x 16 k
            int r  = tid >> 2;
            int kk = (tid & 3) * 4;
            float4 v = *(const float4*)&A[(size_t)(by*64 + r)*K + k0 + kk];
            As[kk+0][r] = v.x; As[kk+1][r] = v.y; As[kk+2][r] = v.z; As[kk+3][r] = v.w;
        }
        {   // B tile: 16 k x 64 cols
            int kk = tid >> 4;
            int c  = (tid & 15) * 4;
            float4 v;
            if (wgB) v = *(const float4*)&B[((size_t)bx*D_H + k0 + kk)*D_HEAD + c];
            else     v = *(const float4*)&B[(size_t)(k0+kk)*N + bx*64 + c];
            Bs[kk][c+0] = v.x; Bs[kk][c+1] = v.y; Bs[kk][c+2] = v.z; Bs[kk][c+3] = v.w;
        }
        __syncthreads();
        #pragma unroll
        for (int k = 0; k < 16; ++k) {
            float4 av = *(const float4*)&As[k][ty*4];
            float4 bv = *(const float4*)&Bs[k][tx*4];
            float a4[4] = {av.x, av.y, av.z, av.w};
            float b4[4] = {bv.x, bv.y, bv.z, bv.w};
            #pragma unroll
            for (int i = 0; i < 4; ++i)
                #pragma unroll
                for (int j = 0; j < 4; ++j)
                    acc[i][j] = fmaf(a4[i], b4[j], acc[i][j]);
        }
        __syncthreads();
    }
    #pragma unroll
    for (int i = 0; i < 4; ++i) {
        int r = by*64 + ty*4 + i;
        #pragma unroll
        for (int j = 0; j < 4; ++j) {
            int c = bx*64 + tx*4 + j;
            float v = acc[i][j] + (bias ? bias[c] : 0.f);
            if (relu) v = fmaxf(v, 0.f);
            C[(size_t)r*N + c] = v;
        }
    }
}

// ---------------- column sums of hh (4096x256) -> S[256], two-stage ----------------
__global__ void colsum1(const float* __restrict__ hh, float* __restrict__ Spart)
{
    int j = threadIdx.x;          // 256 cols
    int b = blockIdx.x;           // 256 blocks x 16 rows
    float s = 0.f;
    #pragma unroll 4
    for (int r = b*16; r < b*16 + 16; ++r) s += hh[(size_t)r*256 + j];
    Spart[b*256 + j] = s;
}

__global__ void colsum2(const float* __restrict__ Spart, float* __restrict__ S)
{
    int j = threadIdx.x;
    float s = 0.f;
    for (int b = 0; b < 256; ++b) s += Spart[b*256 + j];
    S[j] = s;                     // deterministic, no memset needed
}

// ---------------- per-node attention scores ----------------
__global__ __launch_bounds__(256) void score_kernel(
    const float* __restrict__ hh, const float* __restrict__ a_l,
    float* __restrict__ ssrc, float* __restrict__ sdst)
{
    int wid  = (blockIdx.x * 256 + threadIdx.x) >> 6;
    int lane = threadIdx.x & 63;
    if (wid >= NNODES) return;
    int n = wid;
    #pragma unroll
    for (int h = 0; h < NHEAD; ++h) {
        float x  = hh[(size_t)n*256 + h*64 + lane];
        float vs = x * a_l[h*128 + lane];
        float vd = x * a_l[h*128 + 64 + lane];
        #pragma unroll
        for (int off = 32; off; off >>= 1) {
            vs += __shfl_down(vs, off);
            vd += __shfl_down(vd, off);
        }
        if (lane == 0) { ssrc[n*4 + h] = vs; sdst[n*4 + h] = vd; }
    }
}

// ---------------- CSR build ----------------
__global__ __launch_bounds__(1024) void exscan_kernel(
    const int* __restrict__ deg, int* __restrict__ rowptr)
{
    __shared__ int buf[1024];
    int tid = threadIdx.x;
    int base = tid*4;
    int d0 = deg[base], d1 = deg[base+1], d2 = deg[base+2], d3 = deg[base+3];
    int tot = d0+d1+d2+d3;
    buf[tid] = tot;
    __syncthreads();
    for (int off = 1; off < 1024; off <<= 1) {
        int x = 0;
        if (tid >= off) x = buf[tid - off];
        __syncthreads();
        buf[tid] += x;
        __syncthreads();
    }
    int excl = buf[tid] - tot;
    rowptr[base+0] = excl;
    rowptr[base+1] = excl + d0;
    rowptr[base+2] = excl + d0 + d1;
    rowptr[base+3] = excl + d0 + d1 + d2;
    if (tid == 1023) rowptr[4096] = buf[1023];
}

// dedup via bitmap: exactly one scatter per distinct (row,col)
__global__ void scatter_kernel(const int* __restrict__ rows, const int* __restrict__ cols,
                               unsigned* __restrict__ bitmap,
                               const int* __restrict__ rowptr,
                               int* __restrict__ dcnt,
                               int* __restrict__ csr_col)
{
    int k = blockIdx.x*256 + threadIdx.x;
    if (k >= NEDGES) return;
    int n = rows[k], m = cols[k];
    unsigned bit = (unsigned)n*4096u + (unsigned)m;
    unsigned msk = 1u << (bit & 31);
    unsigned old = atomicOr(&bitmap[bit >> 5], msk);
    if (old & msk) return;
    int pos = rowptr[n] + atomicAdd(&dcnt[n], 1);
    csr_col[pos] = m;
}

// ---------------- per-node aggregation + dense-softmax + relu ----------------
// Exact identity for softmax over a row that is 0 at non-edges:
//   M = max(0, max_e e); base = exp(-M)
//   Z = sum_edges(exp(e-M)-base) + N*base
//   hp = [ sum_edges (exp(e-M)-base)*hh[m] + base*S ] / Z
// block = node; wave (tid>>6) = head; lane = output channel.
// CSR row + per-head weights staged in LDS; gathers 4-way unrolled.
__global__ __launch_bounds__(256) void aggregate_kernel(
    const int* __restrict__ rowptr, const int* __restrict__ dcnt,
    const int* __restrict__ csr_col,
    const float* __restrict__ ssrc, const float* __restrict__ sdst,
    const float* __restrict__ hh, const float* __restrict__ S,
    float* __restrict__ hout)
{
    __shared__ int   csr_lds[128];
    __shared__ float w_lds[4*128];
    int n = blockIdx.x;
    int h = threadIdx.x >> 6, o = threadIdx.x & 63;
    int start = rowptr[n], cnt = dcnt[n];
    float ss = ssrc[n*4 + h];

    if (cnt <= 128) {
        // cooperative CSR-row stage (block-uniform branch: syncthreads safe)
        for (int i = threadIdx.x; i < cnt; i += 256) csr_lds[i] = csr_col[start + i];
        __syncthreads();

        // pass 1: row max (baseline 0 from non-edges)
        float mx = 0.f;
        for (int i = o; i < cnt; i += 64) {
            int m = csr_lds[i];
            float e = ss + sdst[m*4 + h];
            e = (e >= 0.f) ? e : 0.2f*e;
            mx = fmaxf(mx, e);
        }
        #pragma unroll
        for (int off = 32; off; off >>= 1) mx = fmaxf(mx, __shfl_xor(mx, off));
        float M = mx;
        float base = expf(-M);

        // weights into LDS + Z partial
        float zp = 0.f;
        for (int i = o; i < cnt; i += 64) {
            int m = csr_lds[i];
            float e = ss + sdst[m*4 + h];
            e = (e >= 0.f) ? e : 0.2f*e;
            float w = expf(e - M) - base;
            w_lds[h*128 + i] = w;
            zp += w;
        }
        #pragma unroll
        for (int off = 32; off; off >>= 1) zp += __shfl_xor(zp, off);

        // accumulate: 4 independent gathers in flight
        float acc = 0.f;
        int i = 0;
        for (; i + 4 <= cnt; i += 4) {
            int m0 = csr_lds[i], m1 = csr_lds[i+1], m2 = csr_lds[i+2], m3 = csr_lds[i+3];
            float w0 = w_lds[h*128+i],   w1 = w_lds[h*128+i+1];
            float w2 = w_lds[h*128+i+2], w3 = w_lds[h*128+i+3];
            float v0 = hh[(size_t)m0*256 + h*64 + o];
            float v1 = hh[(size_t)m1*256 + h*64 + o];
            float v2 = hh[(size_t)m2*256 + h*64 + o];
            float v3 = hh[(size_t)m3*256 + h*64 + o];
            acc += w0*v0; acc += w1*v1; acc += w2*v2; acc += w3*v3;
        }
        for (; i < cnt; ++i)
            acc += w_lds[h*128+i] * hh[(size_t)csr_lds[i]*256 + h*64 + o];

        float Z  = zp + (float)NNODES * base;
        float hp = (acc + base * S[h*64 + o]) / Z;
        hout[(size_t)n*256 + h*64 + o] = fmaxf(hp, 0.f);
    } else {
        // fallback (P ~ 1e-14 for Poisson(32) row): original serial path
        float mx = 0.f;
        for (int i = o; i < cnt; i += 64) {
            int m = csr_col[start + i];
            float e = ss + sdst[m*4 + h];
            e = (e >= 0.f) ? e : 0.2f*e;
            mx = fmaxf(mx, e);
        }
        #pragma unroll
        for (int off = 32; off; off >>= 1) mx = fmaxf(mx, __shfl_xor(mx, off));
        float M = mx;
        float base = expf(-M);
        float zsum = 0.f, acc = 0.f;
        for (int i = 0; i < cnt; ++i) {
            int m = csr_col[start + i];
            float e = ss + sdst[m*4 + h];
            e = (e >= 0.f) ? e : 0.2f*e;
            float c = expf(e - M) - base;
            zsum += c;
            acc += c * hh[(size_t)m*256 + h*64 + o];
        }
        float Z  = zsum + (float)NNODES * base;
        float hp = (acc + base * S[h*64 + o]) / Z;
        hout[(size_t)n*256 + h*64 + o] = fmaxf(hp, 0.f);
    }
}

// ---------------- host: size-based input resolution ----------------
static int find_size(const int* sz, int n, int want, int fallback)
{
    for (int i = 0; i < n; ++i) if (sz[i] == want) return i;
    return fallback;
}

extern "C" void kernel_launch(void* const* d_in, const int* in_sizes, int n_in,
                              void* d_out, int out_size, void* d_ws, size_t ws_size,
                              hipStream_t stream)
{
    int ix   = find_size(in_sizes, n_in, NNODES*D_IN, 0);          // 3145728
    int ie   = find_size(in_sizes, n_in, 2*NEDGES, 1);             // 262144
    if (in_sizes[ie] != 2*NEDGES) ie = find_size(in_sizes, n_in, 4*NEDGES, 1);
    int iwin = find_size(in_sizes, n_in, D_IN*D_H, 2);             // 196608
    int ibin = find_size(in_sizes, n_in, D_H, 3);                  // 256
    int iwg  = find_size(in_sizes, n_in, 2*NHEAD*D_H*D_HEAD, 4);   // 131072
    int ia   = find_size(in_sizes, n_in, 2*NHEAD*2*D_HEAD, 5);     // 1024
    int iwo  = find_size(in_sizes, n_in, D_H*D_OUT, 6);            // 32768
    int ibo  = find_size(in_sizes, n_in, D_OUT, 7);                // 128

    const float* x    = (const float*)d_in[ix];
    const int*   ei   = (const int*)d_in[ie];
    const float* Win  = (const float*)d_in[iwin];
    const float* bin_ = (const float*)d_in[ibin];
    const float* Wg   = (const float*)d_in[iwg];
    const float* a    = (const float*)d_in[ia];
    const float* Wout = (const float*)d_in[iwo];
    const float* bout = (const float*)d_in[ibo];
    float* out = (float*)d_out;

    char* ws = (char*)d_ws;
    float* h0     = (float*)(ws + OFF_H0);
    float* h1     = (float*)(ws + OFF_H1);
    float* hh     = (float*)(ws + OFF_HH);
    float* Spart  = (float*)(ws + OFF_SPART);
    float* ssrc   = (float*)(ws + OFF_SSRC);
    float* sdst   = (float*)(ws + OFF_SDST);
    int*   rowptr = (int*)(ws + OFF_ROWPTR);
    int*   csr    = (int*)(ws + OFF_CSR);
    int*   rows   = (int*)(ws + OFF_ROWS);
    int*   cols   = (int*)(ws + OFF_COLS);
    int*   flag   = (int*)(ws + OFF_FLAG);
    float* S      = (float*)(ws + OFF_S);
    int*   deg    = (int*)(ws + OFF_DEG);
    int*   dcnt   = (int*)(ws + OFF_DCNT);
    unsigned* bitmap = (unsigned*)(ws + OFF_BITMAP);

    // ---- edge normalization + CSR build, once (layer-invariant) ----
    edge_detect<<<1, 64, 0, stream>>>(ei, flag);
    hipMemsetAsync(ws + OFF_ZERO, 0, ZERO_BYTES, stream);   // deg, dcnt, bitmap
    edge_norm<<<NEDGES/256, 256, 0, stream>>>(ei, flag, rows, cols, deg);
    exscan_kernel<<<1, 1024, 0, stream>>>(deg, rowptr);
    scatter_kernel<<<NEDGES/256, 256, 0, stream>>>(rows, cols, bitmap, rowptr, dcnt, csr);

    // ---- input projection: h0 = relu(x @ Win + bin) ----
    {
        dim3 g(D_H/64, NNODES/64);
        gemm_bias_act<<<g, 256, 0, stream>>>(x, Win, bin_, h0, NNODES, D_H, D_IN, 1, 0);
    }

    float* hin = h0;
    float* hcur = h1;
    for (int l = 0; l < 2; ++l) {
        // hh = hin @ Wg[l]  (repack fused into B-load)
        dim3 g2(D_H/64, NNODES/64);
        gemm_bias_act<<<g2, 256, 0, stream>>>(hin, Wg + (size_t)l*NHEAD*D_H*D_HEAD,
                                              nullptr, hh, NNODES, D_H, D_H, 0, 1);

        colsum1<<<256, 256, 0, stream>>>(hh, Spart);
        colsum2<<<1, 256, 0, stream>>>(Spart, S);
        score_kernel<<<NNODES/4, 256, 0, stream>>>(hh, a + (size_t)l*NHEAD*128,
                                                   ssrc, sdst);
        aggregate_kernel<<<NNODES, 256, 0, stream>>>(rowptr, dcnt, csr,
                                                     ssrc, sdst, hh, S, hcur);
        float* t = hin; hin = hcur; hcur = t;
    }

    // ---- output projection -> f32 ----
    {
        dim3 g(D_OUT/64, NNODES/64);
        gemm_bias_act<<<g, 256, 0, stream>>>(hin, Wout, bout, out, NNODES, D_OUT, D_H, 0, 0);
    }
}

// Round 6
// 177.984 us; speedup vs baseline: 1.9606x; 1.1994x over previous
//
#include <hip/hip_runtime.h>
#include <hip/hip_bf16.h>

#define NNODES 4096
#define NEDGES 131072
#define D_IN   768
#define D_H    256
#define NHEAD  4
#define D_HEAD 64
#define D_OUT  128

// ---------------- workspace layout (bytes) ----------------
#define OFF_H0     (0u)
#define OFF_H1     (4u<<20)
#define OFF_HH     (8u<<20)
#define OFF_SPART  (12u<<20)                    // 256*256*4 = 262144
#define OFF_SSRC   (OFF_SPART + 262144u)        // 4096*4*4 = 65536
#define OFF_SDST   (OFF_SSRC + 65536u)          // 65536
#define OFF_ROWPTR (OFF_SDST + 65536u)          // 4097*4 -> pad 16640
#define OFF_CSR    (OFF_ROWPTR + 16640u)        // 131072*4 = 524288
#define OFF_ROWS   (OFF_CSR + 524288u)          // 524288
#define OFF_COLS   (OFF_ROWS + 524288u)         // 524288
#define OFF_FLAG   (OFF_COLS + 524288u)         // 256
#define OFF_S      (OFF_FLAG + 256u)            // 1024
#define OFF_ZERO   (OFF_S + 1024u)              // zeroed-once region
#define OFF_DEG    (OFF_ZERO)                   // 16384
#define OFF_DCNT   (OFF_DEG + 16384u)           // 16384
#define OFF_BITMAP (OFF_DCNT + 16384u)          // 4096*4096/8 = 2097152
#define ZERO_BYTES (16384u + 16384u + 2097152u)

// ---------------- edge dtype autodetect ----------------
__global__ void edge_detect(const int* __restrict__ ei, int* __restrict__ flag)
{
    int t = threadIdx.x;                 // 64 threads, one wave
    int v = ei[2*t + 1];
    unsigned long long ball = __ballot(v == 0);
    if (t == 0) flag[0] = (ball == ~0ull) ? 1 : 0;
}

// normalize edges + histogram degrees (deg must be pre-zeroed)
__global__ void edge_norm(const int* __restrict__ ei, const int* __restrict__ flag,
                          int* __restrict__ rows, int* __restrict__ cols,
                          int* __restrict__ deg)
{
    int k = blockIdx.x*256 + threadIdx.x;
    if (k >= NEDGES) return;
    int is64 = flag[0];
    int r = is64 ? ei[2*k]            : ei[k];
    int c = is64 ? ei[2*NEDGES + 2*k] : ei[NEDGES + k];
    r &= (NNODES-1); c &= (NNODES-1);
    rows[k] = r;
    cols[k] = c;
    atomicAdd(&deg[r], 1);
}

// ---------------- GEMM: C = act(A@B + bias), all f32 ----------------
// 32x64 tile, BK=32, 256 threads, 2x4 micro. Grid (N/64, M/32) = 512 blocks
// for M=4096,N=256 -> 2 blocks/CU (vs 1 before: barrier drains now hidden).
// wgB mode (hh GEMM): B = Wg[l] (H, D_H, D_HEAD); 64-col tile bx = head.
__global__ __launch_bounds__(256) void gemm_bias_act(
    const float* __restrict__ A, const float* __restrict__ B,
    const float* __restrict__ bias, float* __restrict__ C,
    int M, int N, int K, int relu, int wgB)
{
    __shared__ float As[32][34];   // [k][r], float2-read broadcast, pad 34
    __shared__ float Bs[32][68];   // [k][c], float4-read 2-way (free)
    const int tid = threadIdx.x;
    const int bx = blockIdx.x;     // 64-wide N tile
    const int by = blockIdx.y;     // 32-high M tile
    const int tx = tid & 15, ty = tid >> 4;
    const int ar = tid >> 3, ak = (tid & 7) * 4;   // A: row 0..31, k 0..28
    const int bk = tid >> 3, bc = (tid & 7) * 8;   // B: k 0..31, col 0..56
    float acc[2][4] = {};
    for (int k0 = 0; k0 < K; k0 += 32) {
        float4 va = *(const float4*)&A[(size_t)(by*32 + ar)*K + k0 + ak];
        const float* bp = wgB ? &B[((size_t)bx*D_H + k0 + bk)*D_HEAD + bc]
                              : &B[(size_t)(k0 + bk)*N + bx*64 + bc];
        float4 vb0 = *(const float4*)bp;
        float4 vb1 = *(const float4*)(bp + 4);
        As[ak+0][ar] = va.x; As[ak+1][ar] = va.y;
        As[ak+2][ar] = va.z; As[ak+3][ar] = va.w;
        *(float4*)&Bs[bk][bc]     = vb0;
        *(float4*)&Bs[bk][bc + 4] = vb1;
        __syncthreads();
        #pragma unroll
        for (int k = 0; k < 32; ++k) {
            float2 av = *(const float2*)&As[k][ty*2];
            float4 bv = *(const float4*)&Bs[k][tx*4];
            acc[0][0] = fmaf(av.x, bv.x, acc[0][0]);
            acc[0][1] = fmaf(av.x, bv.y, acc[0][1]);
            acc[0][2] = fmaf(av.x, bv.z, acc[0][2]);
            acc[0][3] = fmaf(av.x, bv.w, acc[0][3]);
            acc[1][0] = fmaf(av.y, bv.x, acc[1][0]);
            acc[1][1] = fmaf(av.y, bv.y, acc[1][1]);
            acc[1][2] = fmaf(av.y, bv.z, acc[1][2]);
            acc[1][3] = fmaf(av.y, bv.w, acc[1][3]);
        }
        __syncthreads();
    }
    // epilogue: float4 stores, vectorized bias
    int c = bx*64 + tx*4;
    float4 bv = bias ? *(const float4*)&bias[c] : make_float4(0.f,0.f,0.f,0.f);
    #pragma unroll
    for (int i = 0; i < 2; ++i) {
        int r = by*32 + ty*2 + i;
        float4 v;
        v.x = acc[i][0] + bv.x; v.y = acc[i][1] + bv.y;
        v.z = acc[i][2] + bv.z; v.w = acc[i][3] + bv.w;
        if (relu) {
            v.x = fmaxf(v.x, 0.f); v.y = fmaxf(v.y, 0.f);
            v.z = fmaxf(v.z, 0.f); v.w = fmaxf(v.w, 0.f);
        }
        *(float4*)&C[(size_t)r*N + c] = v;
    }
}

// ---------------- column sums of hh (4096x256) -> S[256], two-stage ----------------
__global__ void colsum1(const float* __restrict__ hh, float* __restrict__ Spart)
{
    int j = threadIdx.x;          // 256 cols
    int b = blockIdx.x;           // 256 blocks x 16 rows
    float s = 0.f;
    #pragma unroll 4
    for (int r = b*16; r < b*16 + 16; ++r) s += hh[(size_t)r*256 + j];
    Spart[b*256 + j] = s;
}

__global__ void colsum2(const float* __restrict__ Spart, float* __restrict__ S)
{
    int j = threadIdx.x;
    float s = 0.f;
    for (int b = 0; b < 256; ++b) s += Spart[b*256 + j];
    S[j] = s;                     // deterministic
}

// ---------------- per-node attention scores ----------------
__global__ __launch_bounds__(256) void score_kernel(
    const float* __restrict__ hh, const float* __restrict__ a_l,
    float* __restrict__ ssrc, float* __restrict__ sdst)
{
    int wid  = (blockIdx.x * 256 + threadIdx.x) >> 6;
    int lane = threadIdx.x & 63;
    if (wid >= NNODES) return;
    int n = wid;
    #pragma unroll
    for (int h = 0; h < NHEAD; ++h) {
        float x  = hh[(size_t)n*256 + h*64 + lane];
        float vs = x * a_l[h*128 + lane];
        float vd = x * a_l[h*128 + 64 + lane];
        #pragma unroll
        for (int off = 32; off; off >>= 1) {
            vs += __shfl_down(vs, off);
            vd += __shfl_down(vd, off);
        }
        if (lane == 0) { ssrc[n*4 + h] = vs; sdst[n*4 + h] = vd; }
    }
}

// ---------------- CSR build ----------------
__global__ __launch_bounds__(1024) void exscan_kernel(
    const int* __restrict__ deg, int* __restrict__ rowptr)
{
    __shared__ int buf[1024];
    int tid = threadIdx.x;
    int base = tid*4;
    int d0 = deg[base], d1 = deg[base+1], d2 = deg[base+2], d3 = deg[base+3];
    int tot = d0+d1+d2+d3;
    buf[tid] = tot;
    __syncthreads();
    for (int off = 1; off < 1024; off <<= 1) {
        int x = 0;
        if (tid >= off) x = buf[tid - off];
        __syncthreads();
        buf[tid] += x;
        __syncthreads();
    }
    int excl = buf[tid] - tot;
    rowptr[base+0] = excl;
    rowptr[base+1] = excl + d0;
    rowptr[base+2] = excl + d0 + d1;
    rowptr[base+3] = excl + d0 + d1 + d2;
    if (tid == 1023) rowptr[4096] = buf[1023];
}

// dedup via bitmap: exactly one scatter per distinct (row,col)
__global__ void scatter_kernel(const int* __restrict__ rows, const int* __restrict__ cols,
                               unsigned* __restrict__ bitmap,
                               const int* __restrict__ rowptr,
                               int* __restrict__ dcnt,
                               int* __restrict__ csr_col)
{
    int k = blockIdx.x*256 + threadIdx.x;
    if (k >= NEDGES) return;
    int n = rows[k], m = cols[k];
    unsigned bit = (unsigned)n*4096u + (unsigned)m;
    unsigned msk = 1u << (bit & 31);
    unsigned old = atomicOr(&bitmap[bit >> 5], msk);
    if (old & msk) return;
    int pos = rowptr[n] + atomicAdd(&dcnt[n], 1);
    csr_col[pos] = m;
}

// ---------------- per-node aggregation + dense-softmax + relu ----------------
// Exact identity for softmax over a row that is 0 at non-edges:
//   M = max(0, max_e e); base = exp(-M)
//   Z = sum_edges(exp(e-M)-base) + N*base
//   hp = [ sum_edges (exp(e-M)-base)*hh[m] + base*S ] / Z
__global__ __launch_bounds__(256) void aggregate_kernel(
    const int* __restrict__ rowptr, const int* __restrict__ dcnt,
    const int* __restrict__ csr_col,
    const float* __restrict__ ssrc, const float* __restrict__ sdst,
    const float* __restrict__ hh, const float* __restrict__ S,
    float* __restrict__ hout)
{
    __shared__ int   csr_lds[128];
    __shared__ float w_lds[4*128];
    int n = blockIdx.x;
    int h = threadIdx.x >> 6, o = threadIdx.x & 63;
    int start = rowptr[n], cnt = dcnt[n];
    float ss = ssrc[n*4 + h];

    if (cnt <= 128) {
        for (int i = threadIdx.x; i < cnt; i += 256) csr_lds[i] = csr_col[start + i];
        __syncthreads();

        float mx = 0.f;
        for (int i = o; i < cnt; i += 64) {
            int m = csr_lds[i];
            float e = ss + sdst[m*4 + h];
            e = (e >= 0.f) ? e : 0.2f*e;
            mx = fmaxf(mx, e);
        }
        #pragma unroll
        for (int off = 32; off; off >>= 1) mx = fmaxf(mx, __shfl_xor(mx, off));
        float M = mx;
        float base = expf(-M);

        float zp = 0.f;
        for (int i = o; i < cnt; i += 64) {
            int m = csr_lds[i];
            float e = ss + sdst[m*4 + h];
            e = (e >= 0.f) ? e : 0.2f*e;
            float w = expf(e - M) - base;
            w_lds[h*128 + i] = w;
            zp += w;
        }
        #pragma unroll
        for (int off = 32; off; off >>= 1) zp += __shfl_xor(zp, off);

        float acc = 0.f;
        int i = 0;
        for (; i + 4 <= cnt; i += 4) {
            int m0 = csr_lds[i], m1 = csr_lds[i+1], m2 = csr_lds[i+2], m3 = csr_lds[i+3];
            float w0 = w_lds[h*128+i],   w1 = w_lds[h*128+i+1];
            float w2 = w_lds[h*128+i+2], w3 = w_lds[h*128+i+3];
            float v0 = hh[(size_t)m0*256 + h*64 + o];
            float v1 = hh[(size_t)m1*256 + h*64 + o];
            float v2 = hh[(size_t)m2*256 + h*64 + o];
            float v3 = hh[(size_t)m3*256 + h*64 + o];
            acc += w0*v0; acc += w1*v1; acc += w2*v2; acc += w3*v3;
        }
        for (; i < cnt; ++i)
            acc += w_lds[h*128+i] * hh[(size_t)csr_lds[i]*256 + h*64 + o];

        float Z  = zp + (float)NNODES * base;
        float hp = (acc + base * S[h*64 + o]) / Z;
        hout[(size_t)n*256 + h*64 + o] = fmaxf(hp, 0.f);
    } else {
        float mx = 0.f;
        for (int i = o; i < cnt; i += 64) {
            int m = csr_col[start + i];
            float e = ss + sdst[m*4 + h];
            e = (e >= 0.f) ? e : 0.2f*e;
            mx = fmaxf(mx, e);
        }
        #pragma unroll
        for (int off = 32; off; off >>= 1) mx = fmaxf(mx, __shfl_xor(mx, off));
        float M = mx;
        float base = expf(-M);
        float zsum = 0.f, acc = 0.f;
        for (int i = 0; i < cnt; ++i) {
            int m = csr_col[start + i];
            float e = ss + sdst[m*4 + h];
            e = (e >= 0.f) ? e : 0.2f*e;
            float c = expf(e - M) - base;
            zsum += c;
            acc += c * hh[(size_t)m*256 + h*64 + o];
        }
        float Z  = zsum + (float)NNODES * base;
        float hp = (acc + base * S[h*64 + o]) / Z;
        hout[(size_t)n*256 + h*64 + o] = fmaxf(hp, 0.f);
    }
}

// ---------------- host: size-based input resolution ----------------
static int find_size(const int* sz, int n, int want, int fallback)
{
    for (int i = 0; i < n; ++i) if (sz[i] == want) return i;
    return fallback;
}

extern "C" void kernel_launch(void* const* d_in, const int* in_sizes, int n_in,
                              void* d_out, int out_size, void* d_ws, size_t ws_size,
                              hipStream_t stream)
{
    int ix   = find_size(in_sizes, n_in, NNODES*D_IN, 0);          // 3145728
    int ie   = find_size(in_sizes, n_in, 2*NEDGES, 1);             // 262144
    if (in_sizes[ie] != 2*NEDGES) ie = find_size(in_sizes, n_in, 4*NEDGES, 1);
    int iwin = find_size(in_sizes, n_in, D_IN*D_H, 2);             // 196608
    int ibin = find_size(in_sizes, n_in, D_H, 3);                  // 256
    int iwg  = find_size(in_sizes, n_in, 2*NHEAD*D_H*D_HEAD, 4);   // 131072
    int ia   = find_size(in_sizes, n_in, 2*NHEAD*2*D_HEAD, 5);     // 1024
    int iwo  = find_size(in_sizes, n_in, D_H*D_OUT, 6);            // 32768
    int ibo  = find_size(in_sizes, n_in, D_OUT, 7);                // 128

    const float* x    = (const float*)d_in[ix];
    const int*   ei   = (const int*)d_in[ie];
    const float* Win  = (const float*)d_in[iwin];
    const float* bin_ = (const float*)d_in[ibin];
    const float* Wg   = (const float*)d_in[iwg];
    const float* a    = (const float*)d_in[ia];
    const float* Wout = (const float*)d_in[iwo];
    const float* bout = (const float*)d_in[ibo];
    float* out = (float*)d_out;

    char* ws = (char*)d_ws;
    float* h0     = (float*)(ws + OFF_H0);
    float* h1     = (float*)(ws + OFF_H1);
    float* hh     = (float*)(ws + OFF_HH);
    float* Spart  = (float*)(ws + OFF_SPART);
    float* ssrc   = (float*)(ws + OFF_SSRC);
    float* sdst   = (float*)(ws + OFF_SDST);
    int*   rowptr = (int*)(ws + OFF_ROWPTR);
    int*   csr    = (int*)(ws + OFF_CSR);
    int*   rows   = (int*)(ws + OFF_ROWS);
    int*   cols   = (int*)(ws + OFF_COLS);
    int*   flag   = (int*)(ws + OFF_FLAG);
    float* S      = (float*)(ws + OFF_S);
    int*   deg    = (int*)(ws + OFF_DEG);
    int*   dcnt   = (int*)(ws + OFF_DCNT);
    unsigned* bitmap = (unsigned*)(ws + OFF_BITMAP);

    // ---- edge normalization + CSR build, once (layer-invariant) ----
    edge_detect<<<1, 64, 0, stream>>>(ei, flag);
    hipMemsetAsync(ws + OFF_ZERO, 0, ZERO_BYTES, stream);   // deg, dcnt, bitmap
    edge_norm<<<NEDGES/256, 256, 0, stream>>>(ei, flag, rows, cols, deg);
    exscan_kernel<<<1, 1024, 0, stream>>>(deg, rowptr);
    scatter_kernel<<<NEDGES/256, 256, 0, stream>>>(rows, cols, bitmap, rowptr, dcnt, csr);

    // ---- input projection: h0 = relu(x @ Win + bin) ----
    {
        dim3 g(D_H/64, NNODES/32);
        gemm_bias_act<<<g, 256, 0, stream>>>(x, Win, bin_, h0, NNODES, D_H, D_IN, 1, 0);
    }

    float* hin = h0;
    float* hcur = h1;
    for (int l = 0; l < 2; ++l) {
        // hh = hin @ Wg[l]  (repack fused into B-load)
        dim3 g2(D_H/64, NNODES/32);
        gemm_bias_act<<<g2, 256, 0, stream>>>(hin, Wg + (size_t)l*NHEAD*D_H*D_HEAD,
                                              nullptr, hh, NNODES, D_H, D_H, 0, 1);

        colsum1<<<256, 256, 0, stream>>>(hh, Spart);
        colsum2<<<1, 256, 0, stream>>>(Spart, S);
        score_kernel<<<NNODES/4, 256, 0, stream>>>(hh, a + (size_t)l*NHEAD*128,
                                                   ssrc, sdst);
        aggregate_kernel<<<NNODES, 256, 0, stream>>>(rowptr, dcnt, csr,
                                                     ssrc, sdst, hh, S, hcur);
        float* t = hin; hin = hcur; hcur = t;
    }

    // ---- output projection -> f32 ----
    {
        dim3 g(D_OUT/64, NNODES/32);
        gemm_bias_act<<<g, 256, 0, stream>>>(hin, Wout, bout, out, NNODES, D_OUT, D_H, 0, 0);
    }
}

// Round 7
// 152.479 us; speedup vs baseline: 2.2885x; 1.1673x over previous
//
#include <hip/hip_runtime.h>
#include <hip/hip_bf16.h>

#define NNODES 4096
#define NEDGES 131072
#define D_IN   768
#define D_H    256
#define NHEAD  4
#define D_HEAD 64
#define D_OUT  128
#define DEGCAP 192

// ---------------- workspace layout (bytes) ----------------
#define OFF_H0     (0u)
#define OFF_H1     (4u<<20)
#define OFF_HH     (8u<<20)
#define OFF_SPART  (12u<<20)                    // 128*256*4 = 131072
#define OFF_SSRC   (OFF_SPART + 131072u)        // 4096*4*4 = 65536
#define OFF_SDST   (OFF_SSRC + 65536u)          // 65536
#define OFF_S      (OFF_SDST + 65536u)          // 1024
#define OFF_BM     (OFF_S + 1024u)              // 4096*128 words = 2MB
#define BM_BYTES   ((size_t)NNODES*128u*4u)

// ---------------- adjacency bitmap (fused dtype autodetect; idempotent) ----------------
// int64-pushed edges have all-zero high int32 words (values < 4096); genuine
// int32 edges have random node ids in odd slots -> P(first 64 all zero) ~ 4096^-64.
__global__ void edge_bitmap(const int* __restrict__ ei, unsigned* __restrict__ bm)
{
    __shared__ int is64_sh;
    int tid = threadIdx.x;
    if (tid < 64) {
        int v = ei[2*tid + 1];
        unsigned long long ball = __ballot(v == 0);
        if (tid == 0) is64_sh = (ball == ~0ull) ? 1 : 0;
    }
    __syncthreads();
    int is64 = is64_sh;
    int k = blockIdx.x*256 + tid;
    if (k >= NEDGES) return;
    int r = is64 ? ei[2*k]            : ei[k];
    int c = is64 ? ei[2*NEDGES + 2*k] : ei[NEDGES + k];
    r &= (NNODES-1); c &= (NNODES-1);
    atomicOr(&bm[(size_t)r*128 + (c>>5)], 1u << (c & 31));
}

// ---------------- GEMM: C = act(A@B + bias), f32, optional fused epilogue ----
// 32x64 tile, BK=32, 128 threads, 4x4 micro (16 FMA per 2 ds_read_b128).
// wgB: B = Wg[l] with layout (H, D_H, D_HEAD); 64-col tile bx == head.
// a_l != nullptr (hh GEMM): epilogue also computes per-row attention scores
// ssrc/sdst (tx-shuffle reduce) and per-column partial sums Spart[by][*].
__global__ __launch_bounds__(128) void gemm_fused(
    const float* __restrict__ A, const float* __restrict__ B,
    const float* __restrict__ bias, float* __restrict__ C,
    int M, int N, int K, int relu, int wgB,
    const float* __restrict__ a_l, float* __restrict__ ssrc,
    float* __restrict__ sdst, float* __restrict__ Spart)
{
    __shared__ float As[32][34];   // [k][row], pad->2-way writes (free)
    __shared__ float Bs[32][68];   // [k][col]
    __shared__ float cs[8][64];    // epilogue column partials
    const int tid = threadIdx.x;
    const int bx = blockIdx.x;     // 64-wide N tile (== head in wgB mode)
    const int by = blockIdx.y;     // 32-high M tile
    const int tx = tid & 15, ty = tid >> 4;          // micro: 4 rows x 4 cols
    const int lr = tid >> 2, lk = (tid & 3) * 8;     // A stage: 32r x 32k
    const int r8 = tid >> 4, cq = (tid & 15) * 4;    // B stage: 8 rows/round
    float acc[4][4] = {};
    for (int k0 = 0; k0 < K; k0 += 32) {
        float4 va0 = *(const float4*)&A[(size_t)(by*32 + lr)*K + k0 + lk];
        float4 va1 = *(const float4*)&A[(size_t)(by*32 + lr)*K + k0 + lk + 4];
        float4 vb[4];
        #pragma unroll
        for (int p = 0; p < 4; ++p) {
            int kk = k0 + r8 + 8*p;
            const float* bp = wgB ? &B[((size_t)bx*D_H + kk)*D_HEAD + cq]
                                  : &B[(size_t)kk*N + bx*64 + cq];
            vb[p] = *(const float4*)bp;
        }
        As[lk+0][lr] = va0.x; As[lk+1][lr] = va0.y;
        As[lk+2][lr] = va0.z; As[lk+3][lr] = va0.w;
        As[lk+4][lr] = va1.x; As[lk+5][lr] = va1.y;
        As[lk+6][lr] = va1.z; As[lk+7][lr] = va1.w;
        #pragma unroll
        for (int p = 0; p < 4; ++p)
            *(float4*)&Bs[r8 + 8*p][cq] = vb[p];
        __syncthreads();
        #pragma unroll
        for (int k = 0; k < 32; ++k) {
            float4 av = *(const float4*)&As[k][ty*4];
            float4 bv = *(const float4*)&Bs[k][tx*4];
            float a4[4] = {av.x, av.y, av.z, av.w};
            float b4[4] = {bv.x, bv.y, bv.z, bv.w};
            #pragma unroll
            for (int i = 0; i < 4; ++i)
                #pragma unroll
                for (int j = 0; j < 4; ++j)
                    acc[i][j] = fmaf(a4[i], b4[j], acc[i][j]);
        }
        __syncthreads();
    }
    // ---- C store (float4, vectorized bias) ----
    int c = bx*64 + tx*4;
    float4 bv4 = bias ? *(const float4*)&bias[c] : make_float4(0.f,0.f,0.f,0.f);
    #pragma unroll
    for (int i = 0; i < 4; ++i) {
        int r = by*32 + ty*4 + i;
        float4 v;
        v.x = acc[i][0] + bv4.x; v.y = acc[i][1] + bv4.y;
        v.z = acc[i][2] + bv4.z; v.w = acc[i][3] + bv4.w;
        if (relu) {
            v.x = fmaxf(v.x, 0.f); v.y = fmaxf(v.y, 0.f);
            v.z = fmaxf(v.z, 0.f); v.w = fmaxf(v.w, 0.f);
        }
        *(float4*)&C[(size_t)r*N + c] = v;
    }
    // ---- fused epilogue: scores + column partial sums (hh GEMM only) ----
    if (a_l) {
        int h = bx;
        float4 asv = *(const float4*)&a_l[h*128 + tx*4];
        float4 adv = *(const float4*)&a_l[h*128 + 64 + tx*4];
        #pragma unroll
        for (int i = 0; i < 4; ++i) {
            float ps = acc[i][0]*asv.x + acc[i][1]*asv.y
                     + acc[i][2]*asv.z + acc[i][3]*asv.w;
            float pd = acc[i][0]*adv.x + acc[i][1]*adv.y
                     + acc[i][2]*adv.z + acc[i][3]*adv.w;
            #pragma unroll
            for (int off = 1; off < 16; off <<= 1) {
                ps += __shfl_xor(ps, off);
                pd += __shfl_xor(pd, off);
            }
            if (tx == 0) {
                int r = by*32 + ty*4 + i;
                ssrc[r*4 + h] = ps;
                sdst[r*4 + h] = pd;
            }
        }
        #pragma unroll
        for (int j = 0; j < 4; ++j)
            cs[ty][tx*4 + j] = acc[0][j] + acc[1][j] + acc[2][j] + acc[3][j];
        __syncthreads();
        if (tid < 64) {
            float s = 0.f;
            #pragma unroll
            for (int t = 0; t < 8; ++t) s += cs[t][tid];
            Spart[by*256 + h*64 + tid] = s;
        }
    }
}

// ---------------- colsum stage 2: S[c] = sum_by Spart[by][c] ----------------
__global__ void colsum2(const float* __restrict__ Spart, float* __restrict__ S)
{
    int j = threadIdx.x;
    float s = 0.f;
    for (int b = 0; b < 128; ++b) s += Spart[b*256 + j];
    S[j] = s;                     // deterministic
}

// ---------------- per-node aggregation + dense-softmax + relu ----------------
// Neighbor list built in-kernel from the bitmap row (wave-0 popcount +
// shfl-prefix compaction; dedup inherent). Exact dense-softmax identity:
//   M = max(0, max_e e); base = exp(-M)
//   Z = sum_edges(exp(e-M)-base) + N*base
//   hp = [ sum_edges (exp(e-M)-base)*hh[m] + base*S ] / Z
// block = node; wave (tid>>6) = head; lane = output channel.
__global__ __launch_bounds__(256) void aggregate_kernel(
    const unsigned* __restrict__ bm,
    const float* __restrict__ ssrc, const float* __restrict__ sdst,
    const float* __restrict__ hh, const float* __restrict__ S,
    float* __restrict__ hout)
{
    __shared__ int   csr_lds[DEGCAP];
    __shared__ float w_lds[4*DEGCAP];
    __shared__ int   cnt_sh;
    int n = blockIdx.x;
    int tid = threadIdx.x;
    int h = tid >> 6, o = tid & 63;
    const unsigned* brow = bm + (size_t)n*128;

    // wave 0: compact bitmap row -> neighbor list
    if (tid < 64) {
        unsigned wA = brow[2*tid], wB = brow[2*tid + 1];
        int c = __popc(wA) + __popc(wB);
        int pre = c;
        #pragma unroll
        for (int off = 1; off < 64; off <<= 1) {
            int v = __shfl_up(pre, off);
            if (tid >= off) pre += v;
        }
        int excl = pre - c;
        int total = __shfl(pre, 63);
        if (total <= DEGCAP) {
            int pos = excl, base = tid*64;
            unsigned w = wA;
            while (w) { int b = __builtin_ctz(w); csr_lds[pos++] = base + b; w &= w-1; }
            w = wB; base += 32;
            while (w) { int b = __builtin_ctz(w); csr_lds[pos++] = base + b; w &= w-1; }
        }
        if (tid == 0) cnt_sh = total;
    }
    __syncthreads();
    int cnt = cnt_sh;
    float ss = ssrc[n*4 + h];

    if (cnt <= DEGCAP) {
        // pass 1: row max (baseline 0 from non-edges)
        float mx = 0.f;
        for (int i = o; i < cnt; i += 64) {
            int m = csr_lds[i];
            float e = ss + sdst[m*4 + h];
            e = (e >= 0.f) ? e : 0.2f*e;
            mx = fmaxf(mx, e);
        }
        #pragma unroll
        for (int off = 32; off; off >>= 1) mx = fmaxf(mx, __shfl_xor(mx, off));
        float M = mx;
        float base = expf(-M);

        // weights into LDS + Z partial (same-wave LDS ordering: no barrier)
        float zp = 0.f;
        for (int i = o; i < cnt; i += 64) {
            int m = csr_lds[i];
            float e = ss + sdst[m*4 + h];
            e = (e >= 0.f) ? e : 0.2f*e;
            float w = expf(e - M) - base;
            w_lds[h*DEGCAP + i] = w;
            zp += w;
        }
        #pragma unroll
        for (int off = 32; off; off >>= 1) zp += __shfl_xor(zp, off);

        // accumulate: 4 independent gathers in flight
        float acc = 0.f;
        int i = 0;
        for (; i + 4 <= cnt; i += 4) {
            int m0 = csr_lds[i],   m1 = csr_lds[i+1];
            int m2 = csr_lds[i+2], m3 = csr_lds[i+3];
            float w0 = w_lds[h*DEGCAP+i],   w1 = w_lds[h*DEGCAP+i+1];
            float w2 = w_lds[h*DEGCAP+i+2], w3 = w_lds[h*DEGCAP+i+3];
            float v0 = hh[(size_t)m0*256 + h*64 + o];
            float v1 = hh[(size_t)m1*256 + h*64 + o];
            float v2 = hh[(size_t)m2*256 + h*64 + o];
            float v3 = hh[(size_t)m3*256 + h*64 + o];
            acc += w0*v0; acc += w1*v1; acc += w2*v2; acc += w3*v3;
        }
        for (; i < cnt; ++i)
            acc += w_lds[h*DEGCAP+i] * hh[(size_t)csr_lds[i]*256 + h*64 + o];

        float Z  = zp + (float)NNODES * base;
        float hp = (acc + base * S[h*64 + o]) / Z;
        hout[(size_t)n*256 + h*64 + o] = fmaxf(hp, 0.f);
    } else {
        // overflow fallback (never expected for Poisson(32) rows): direct scan
        float mx = 0.f;
        for (int m = o; m < NNODES; m += 64) {
            if ((brow[m>>5] >> (m & 31)) & 1u) {
                float e = ss + sdst[m*4 + h];
                e = (e >= 0.f) ? e : 0.2f*e;
                mx = fmaxf(mx, e);
            }
        }
        #pragma unroll
        for (int off = 32; off; off >>= 1) mx = fmaxf(mx, __shfl_xor(mx, off));
        float M = mx;
        float base = expf(-M);
        float zp = 0.f, acc = 0.f;
        for (int m = 0; m < NNODES; ++m) {
            if ((brow[m>>5] >> (m & 31)) & 1u) {
                float e = ss + sdst[m*4 + h];
                e = (e >= 0.f) ? e : 0.2f*e;
                float w = expf(e - M) - base;
                zp += w;
                acc += w * hh[(size_t)m*256 + h*64 + o];
            }
        }
        float Z  = zp + (float)NNODES * base;
        float hp = (acc + base * S[h*64 + o]) / Z;
        hout[(size_t)n*256 + h*64 + o] = fmaxf(hp, 0.f);
    }
}

// ---------------- host: size-based input resolution ----------------
static int find_size(const int* sz, int n, int want, int fallback)
{
    for (int i = 0; i < n; ++i) if (sz[i] == want) return i;
    return fallback;
}

extern "C" void kernel_launch(void* const* d_in, const int* in_sizes, int n_in,
                              void* d_out, int out_size, void* d_ws, size_t ws_size,
                              hipStream_t stream)
{
    int ix   = find_size(in_sizes, n_in, NNODES*D_IN, 0);          // 3145728
    int ie   = find_size(in_sizes, n_in, 2*NEDGES, 1);             // 262144
    int iwin = find_size(in_sizes, n_in, D_IN*D_H, 2);             // 196608
    int ibin = find_size(in_sizes, n_in, D_H, 3);                  // 256
    int iwg  = find_size(in_sizes, n_in, 2*NHEAD*D_H*D_HEAD, 4);   // 131072
    int ia   = find_size(in_sizes, n_in, 2*NHEAD*2*D_HEAD, 5);     // 1024
    int iwo  = find_size(in_sizes, n_in, D_H*D_OUT, 6);            // 32768
    int ibo  = find_size(in_sizes, n_in, D_OUT, 7);                // 128

    const float* x    = (const float*)d_in[ix];
    const int*   ei   = (const int*)d_in[ie];
    const float* Win  = (const float*)d_in[iwin];
    const float* bin_ = (const float*)d_in[ibin];
    const float* Wg   = (const float*)d_in[iwg];
    const float* a    = (const float*)d_in[ia];
    const float* Wout = (const float*)d_in[iwo];
    const float* bout = (const float*)d_in[ibo];
    float* out = (float*)d_out;

    char* ws = (char*)d_ws;
    float*    h0    = (float*)(ws + OFF_H0);
    float*    h1    = (float*)(ws + OFF_H1);
    float*    hh    = (float*)(ws + OFF_HH);
    float*    Spart = (float*)(ws + OFF_SPART);
    float*    ssrc  = (float*)(ws + OFF_SSRC);
    float*    sdst  = (float*)(ws + OFF_SDST);
    float*    S     = (float*)(ws + OFF_S);
    unsigned* bm    = (unsigned*)(ws + OFF_BM);

    // ---- adjacency bitmap, once (edges are layer-invariant) ----
    hipMemsetAsync(bm, 0, BM_BYTES, stream);
    edge_bitmap<<<NEDGES/256, 256, 0, stream>>>(ei, bm);

    // ---- input projection: h0 = relu(x @ Win + bin) ----
    {
        dim3 g(D_H/64, NNODES/32);
        gemm_fused<<<g, 128, 0, stream>>>(x, Win, bin_, h0, NNODES, D_H, D_IN, 1, 0,
                                          nullptr, nullptr, nullptr, nullptr);
    }

    float* hin = h0;
    float* hcur = h1;
    for (int l = 0; l < 2; ++l) {
        // hh = hin @ Wg[l]  (+ fused scores & column partial sums)
        dim3 g2(D_H/64, NNODES/32);
        gemm_fused<<<g2, 128, 0, stream>>>(hin, Wg + (size_t)l*NHEAD*D_H*D_HEAD,
                                           nullptr, hh, NNODES, D_H, D_H, 0, 1,
                                           a + (size_t)l*NHEAD*128, ssrc, sdst, Spart);
        colsum2<<<1, 256, 0, stream>>>(Spart, S);
        aggregate_kernel<<<NNODES, 256, 0, stream>>>(bm, ssrc, sdst, hh, S, hcur);
        float* t = hin; hin = hcur; hcur = t;
    }

    // ---- output projection -> f32 ----
    {
        dim3 g(D_OUT/64, NNODES/32);
        gemm_fused<<<g, 128, 0, stream>>>(hin, Wout, bout, out, NNODES, D_OUT, D_H, 0, 0,
                                          nullptr, nullptr, nullptr, nullptr);
    }
}

// Round 8
// 95.849 us; speedup vs baseline: 3.6406x; 1.5908x over previous
//
#include <hip/hip_runtime.h>
#include <hip/hip_bf16.h>

#define NNODES 4096
#define NEDGES 131072
#define D_IN   768
#define D_H    256
#define NHEAD  4
#define D_HEAD 64
#define D_OUT  128
#define DEGCAP 192

typedef __attribute__((ext_vector_type(4))) float f32x4;
typedef __attribute__((ext_vector_type(8))) short bf16x8;
typedef __attribute__((ext_vector_type(8))) unsigned short u16x8;

static __device__ __forceinline__ unsigned short f2bf(float f) {
    __hip_bfloat16 h = __float2bfloat16(f);
    return *reinterpret_cast<unsigned short*>(&h);
}
static __device__ __forceinline__ float bf2f(unsigned short u) {
    return __uint_as_float((unsigned)u << 16);
}

// ---------------- workspace layout (bytes) ----------------
#define OFF_H0     (0u)                          // 4096*256*4 = 4MB (f32)
#define OFF_H1     (4u<<20)                      // 4MB (f32)
#define OFF_HH     (8u<<20)                      // 4096*256*2 = 2MB (bf16)
#define OFF_SPART  (10u<<20)                     // 128*256*4 = 131072
#define OFF_SSRC   (OFF_SPART + 131072u)         // 65536
#define OFF_SDST   (OFF_SSRC + 65536u)           // 65536
#define OFF_S      (OFF_SDST + 65536u)           // 1024
#define OFF_WINT   (OFF_S + 1024u)               // 256*768*2 = 393216
#define OFF_WGT    (OFF_WINT + 393216u)          // 8*64*256*2 = 262144
#define OFF_WOUTT  (OFF_WGT + 262144u)           // 128*256*2 = 65536
#define OFF_BM     (OFF_WOUTT + 65536u)          // 2MB
#define BM_BYTES   ((size_t)NNODES*128u*4u)

// ---------------- adjacency bitmap (fused dtype autodetect; idempotent) ----------------
__global__ void edge_bitmap(const int* __restrict__ ei, unsigned* __restrict__ bm)
{
    __shared__ int is64_sh;
    int tid = threadIdx.x;
    if (tid < 64) {
        int v = ei[2*tid + 1];
        unsigned long long ball = __ballot(v == 0);
        if (tid == 0) is64_sh = (ball == ~0ull) ? 1 : 0;
    }
    __syncthreads();
    int is64 = is64_sh;
    int k = blockIdx.x*256 + tid;
    if (k >= NEDGES) return;
    int r = is64 ? ei[2*k]            : ei[k];
    int c = is64 ? ei[2*NEDGES + 2*k] : ei[NEDGES + k];
    r &= (NNODES-1); c &= (NNODES-1);
    atomicOr(&bm[(size_t)r*128 + (c>>5)], 1u << (c & 31));
}

// ---------------- weight transpose + f32->bf16 convert (once per call) ----------------
// mat 0: Win (768x256) -> WinT[256][768]; mats 1..8: Wg[lh] (256x64) -> WgT[lh][64][256];
// mat 9: Wout (256x128) -> WoutT[128][256].
__global__ __launch_bounds__(256) void convert_weights(
    const float* __restrict__ Win, const float* __restrict__ Wg,
    const float* __restrict__ Wout,
    unsigned short* __restrict__ WinT, unsigned short* __restrict__ WgT,
    unsigned short* __restrict__ WoutT)
{
    __shared__ float tile[32][33];
    int mat = blockIdx.y;
    const float* src; unsigned short* dst; int R, Cc;
    if (mat == 0)      { src = Win;                 dst = WinT;                 R = 768; Cc = 256; }
    else if (mat <= 8) { src = Wg + (size_t)(mat-1)*256*64; dst = WgT + (size_t)(mat-1)*64*256; R = 256; Cc = 64; }
    else               { src = Wout;                dst = WoutT;                R = 256; Cc = 128; }
    int tilesC = Cc >> 5;
    int tr = blockIdx.x / tilesC, tc = blockIdx.x % tilesC;
    if (tr*32 >= R) return;
    int ci = threadIdx.x & 31, rq = threadIdx.x >> 5;
    #pragma unroll
    for (int rr = rq; rr < 32; rr += 8)
        tile[rr][ci] = src[(size_t)(tr*32+rr)*Cc + tc*32 + ci];
    __syncthreads();
    int ri = threadIdx.x & 31, cq = threadIdx.x >> 5;
    #pragma unroll
    for (int cc = cq; cc < 32; cc += 8)
        dst[(size_t)(tc*32+cc)*R + tr*32 + ri] = f2bf(tile[ri][cc]);
}

// ---------------- MFMA GEMM: C = act(A@B + bias) ----------------
// A: MxK f32 (converted to bf16 during staging). BT: NxK bf16 (pre-transposed).
// 32x64 tile, BK=32, 256 thr = 4 waves (wave = 16-col strip), 2 MFMA/wave/K-step.
// Frags (verified layout): A/B lane holds free-idx=lane&15, k=(lane>>4)*8+i;
// D: row=(lane>>4)*4+i (+16*t), col=lane&15.
// a_l != null: epilogue computes ssrc/sdst (row dot a_src/a_dst) + Spart col sums,
// and C is stored bf16 (Cb); else f32 (Cf).
__global__ __launch_bounds__(256) void gemm_mfma(
    const float* __restrict__ A, const unsigned short* __restrict__ BT,
    const float* __restrict__ bias, float* __restrict__ Cf,
    unsigned short* __restrict__ Cb,
    int M, int N, int K, int relu,
    const float* __restrict__ a_l, float* __restrict__ ssrc,
    float* __restrict__ sdst, float* __restrict__ Spart)
{
    __shared__ unsigned short As[32][56];   // [row][k] bf16, stride 112B (16B-mult, 2-way banks)
    __shared__ unsigned short Bs[64][56];   // [col][k] bf16
    __shared__ float sredS[4][32], sredD[4][32];
    const int tid = threadIdx.x;
    const int bx = blockIdx.x, by = blockIdx.y;
    const int wc = tid >> 6;                 // wave id = column strip
    const int lane = tid & 63;
    const int g = lane >> 4, c = lane & 15;
    const int ar = tid >> 3, ak = (tid & 7) * 4;   // A stage: 32 rows x (8thr x float4)
    const int bc = tid >> 2, bk = (tid & 3) * 8;   // B stage: 64 cols x (4thr x u16x8)
    f32x4 acc0 = {0.f,0.f,0.f,0.f}, acc1 = {0.f,0.f,0.f,0.f};
    const float* Arow = A + (size_t)(by*32 + ar)*K;
    const unsigned short* Brow = BT + (size_t)(bx*64 + bc)*K;

    for (int k0 = 0; k0 < K; k0 += 32) {
        float4 av = *(const float4*)&Arow[k0 + ak];
        u16x8 bv = *(const u16x8*)&Brow[k0 + bk];
        ushort4 aw;
        aw.x = f2bf(av.x); aw.y = f2bf(av.y); aw.z = f2bf(av.z); aw.w = f2bf(av.w);
        *(ushort4*)&As[ar][ak] = aw;
        *(u16x8*)&Bs[bc][bk] = bv;
        __syncthreads();
        bf16x8 bfrag = *(bf16x8*)&Bs[wc*16 + c][g*8];
        bf16x8 a0    = *(bf16x8*)&As[c][g*8];
        bf16x8 a1    = *(bf16x8*)&As[16 + c][g*8];
        acc0 = __builtin_amdgcn_mfma_f32_16x16x32_bf16(a0, bfrag, acc0, 0, 0, 0);
        acc1 = __builtin_amdgcn_mfma_f32_16x16x32_bf16(a1, bfrag, acc1, 0, 0, 0);
        __syncthreads();
    }

    // ---- C store ----
    const int col = bx*64 + wc*16 + c;
    float bb = bias ? bias[col] : 0.f;
    #pragma unroll
    for (int t = 0; t < 2; ++t) {
        f32x4 av = t ? acc1 : acc0;
        #pragma unroll
        for (int i = 0; i < 4; ++i) {
            int r = by*32 + t*16 + g*4 + i;
            float v = av[i] + bb;
            if (relu) v = fmaxf(v, 0.f);
            if (Cb) Cb[(size_t)r*N + col] = f2bf(v);
            else    Cf[(size_t)r*N + col] = v;
        }
    }

    // ---- fused epilogue: attention scores + column partial sums ----
    if (a_l) {
        int h = bx;
        float as = a_l[h*128 + wc*16 + c];
        float ad = a_l[h*128 + 64 + wc*16 + c];
        float ps[8], pd[8], cs = 0.f;
        #pragma unroll
        for (int t = 0; t < 2; ++t) {
            f32x4 av = t ? acc1 : acc0;
            #pragma unroll
            for (int i = 0; i < 4; ++i) {
                ps[t*4+i] = av[i] * as;
                pd[t*4+i] = av[i] * ad;
                cs += av[i];
            }
        }
        #pragma unroll
        for (int off = 1; off < 16; off <<= 1) {
            #pragma unroll
            for (int j = 0; j < 8; ++j) {
                ps[j] += __shfl_xor(ps[j], off);
                pd[j] += __shfl_xor(pd[j], off);
            }
        }
        if (c == 0) {
            #pragma unroll
            for (int t = 0; t < 2; ++t)
                #pragma unroll
                for (int i = 0; i < 4; ++i) {
                    sredS[wc][t*16 + g*4 + i] = ps[t*4+i];
                    sredD[wc][t*16 + g*4 + i] = pd[t*4+i];
                }
        }
        // column sums over 32 rows: reduce across g-groups
        cs += __shfl_xor(cs, 16);
        cs += __shfl_xor(cs, 32);
        if (g == 0)
            Spart[by*256 + h*64 + wc*16 + c] = cs;
        __syncthreads();
        if (tid < 32) {
            float s1 = sredS[0][tid] + sredS[1][tid] + sredS[2][tid] + sredS[3][tid];
            float s2 = sredD[0][tid] + sredD[1][tid] + sredD[2][tid] + sredD[3][tid];
            int r = by*32 + tid;
            ssrc[r*4 + h] = s1;
            sdst[r*4 + h] = s2;
        }
    }
}

// ---------------- colsum stage 2: S[c] = sum_by Spart[by][c] ----------------
__global__ void colsum2(const float* __restrict__ Spart, float* __restrict__ S)
{
    int j = threadIdx.x;
    float s = 0.f;
    for (int b = 0; b < 128; ++b) s += Spart[b*256 + j];
    S[j] = s;                     // deterministic
}

// ---------------- per-node aggregation + dense-softmax + relu ----------------
// Neighbor list built in-kernel from the bitmap row. Exact dense-softmax identity:
//   M = max(0, max_e e); base = exp(-M)
//   Z = sum_edges(exp(e-M)-base) + N*base
//   hp = [ sum_edges (exp(e-M)-base)*hh[m] + base*S ] / Z
// hh is bf16 (exact-convert gathers); block = node; wave = head; lane = channel.
__global__ __launch_bounds__(256) void aggregate_kernel(
    const unsigned* __restrict__ bm,
    const float* __restrict__ ssrc, const float* __restrict__ sdst,
    const unsigned short* __restrict__ hh, const float* __restrict__ S,
    float* __restrict__ hout)
{
    __shared__ int   csr_lds[DEGCAP];
    __shared__ float w_lds[4*DEGCAP];
    __shared__ int   cnt_sh;
    int n = blockIdx.x;
    int tid = threadIdx.x;
    int h = tid >> 6, o = tid & 63;
    const unsigned* brow = bm + (size_t)n*128;

    if (tid < 64) {
        unsigned wA = brow[2*tid], wB = brow[2*tid + 1];
        int cpc = __popc(wA) + __popc(wB);
        int pre = cpc;
        #pragma unroll
        for (int off = 1; off < 64; off <<= 1) {
            int v = __shfl_up(pre, off);
            if (tid >= off) pre += v;
        }
        int excl = pre - cpc;
        int total = __shfl(pre, 63);
        if (total <= DEGCAP) {
            int pos = excl, base = tid*64;
            unsigned w = wA;
            while (w) { int b = __builtin_ctz(w); csr_lds[pos++] = base + b; w &= w-1; }
            w = wB; base += 32;
            while (w) { int b = __builtin_ctz(w); csr_lds[pos++] = base + b; w &= w-1; }
        }
        if (tid == 0) cnt_sh = total;
    }
    __syncthreads();
    int cnt = cnt_sh;
    float ss = ssrc[n*4 + h];

    if (cnt <= DEGCAP) {
        float mx = 0.f;
        for (int i = o; i < cnt; i += 64) {
            int m = csr_lds[i];
            float e = ss + sdst[m*4 + h];
            e = (e >= 0.f) ? e : 0.2f*e;
            mx = fmaxf(mx, e);
        }
        #pragma unroll
        for (int off = 32; off; off >>= 1) mx = fmaxf(mx, __shfl_xor(mx, off));
        float M = mx;
        float base = expf(-M);

        float zp = 0.f;
        for (int i = o; i < cnt; i += 64) {
            int m = csr_lds[i];
            float e = ss + sdst[m*4 + h];
            e = (e >= 0.f) ? e : 0.2f*e;
            float w = expf(e - M) - base;
            w_lds[h*DEGCAP + i] = w;
            zp += w;
        }
        #pragma unroll
        for (int off = 32; off; off >>= 1) zp += __shfl_xor(zp, off);

        float acc = 0.f;
        int i = 0;
        for (; i + 4 <= cnt; i += 4) {
            int m0 = csr_lds[i],   m1 = csr_lds[i+1];
            int m2 = csr_lds[i+2], m3 = csr_lds[i+3];
            float w0 = w_lds[h*DEGCAP+i],   w1 = w_lds[h*DEGCAP+i+1];
            float w2 = w_lds[h*DEGCAP+i+2], w3 = w_lds[h*DEGCAP+i+3];
            float v0 = bf2f(hh[(size_t)m0*256 + h*64 + o]);
            float v1 = bf2f(hh[(size_t)m1*256 + h*64 + o]);
            float v2 = bf2f(hh[(size_t)m2*256 + h*64 + o]);
            float v3 = bf2f(hh[(size_t)m3*256 + h*64 + o]);
            acc += w0*v0; acc += w1*v1; acc += w2*v2; acc += w3*v3;
        }
        for (; i < cnt; ++i)
            acc += w_lds[h*DEGCAP+i] * bf2f(hh[(size_t)csr_lds[i]*256 + h*64 + o]);

        float Z  = zp + (float)NNODES * base;
        float hp = (acc + base * S[h*64 + o]) / Z;
        hout[(size_t)n*256 + h*64 + o] = fmaxf(hp, 0.f);
    } else {
        float mx = 0.f;
        for (int m = o; m < NNODES; m += 64) {
            if ((brow[m>>5] >> (m & 31)) & 1u) {
                float e = ss + sdst[m*4 + h];
                e = (e >= 0.f) ? e : 0.2f*e;
                mx = fmaxf(mx, e);
            }
        }
        #pragma unroll
        for (int off = 32; off; off >>= 1) mx = fmaxf(mx, __shfl_xor(mx, off));
        float M = mx;
        float base = expf(-M);
        float zp = 0.f, acc = 0.f;
        for (int m = 0; m < NNODES; ++m) {
            if ((brow[m>>5] >> (m & 31)) & 1u) {
                float e = ss + sdst[m*4 + h];
                e = (e >= 0.f) ? e : 0.2f*e;
                float w = expf(e - M) - base;
                zp += w;
                acc += w * bf2f(hh[(size_t)m*256 + h*64 + o]);
            }
        }
        float Z  = zp + (float)NNODES * base;
        float hp = (acc + base * S[h*64 + o]) / Z;
        hout[(size_t)n*256 + h*64 + o] = fmaxf(hp, 0.f);
    }
}

// ---------------- host: size-based input resolution ----------------
static int find_size(const int* sz, int n, int want, int fallback)
{
    for (int i = 0; i < n; ++i) if (sz[i] == want) return i;
    return fallback;
}

extern "C" void kernel_launch(void* const* d_in, const int* in_sizes, int n_in,
                              void* d_out, int out_size, void* d_ws, size_t ws_size,
                              hipStream_t stream)
{
    int ix   = find_size(in_sizes, n_in, NNODES*D_IN, 0);          // 3145728
    int ie   = find_size(in_sizes, n_in, 2*NEDGES, 1);             // 262144
    int iwin = find_size(in_sizes, n_in, D_IN*D_H, 2);             // 196608
    int ibin = find_size(in_sizes, n_in, D_H, 3);                  // 256
    int iwg  = find_size(in_sizes, n_in, 2*NHEAD*D_H*D_HEAD, 4);   // 131072
    int ia   = find_size(in_sizes, n_in, 2*NHEAD*2*D_HEAD, 5);     // 1024
    int iwo  = find_size(in_sizes, n_in, D_H*D_OUT, 6);            // 32768
    int ibo  = find_size(in_sizes, n_in, D_OUT, 7);                // 128

    const float* x    = (const float*)d_in[ix];
    const int*   ei   = (const int*)d_in[ie];
    const float* Win  = (const float*)d_in[iwin];
    const float* bin_ = (const float*)d_in[ibin];
    const float* Wg   = (const float*)d_in[iwg];
    const float* a    = (const float*)d_in[ia];
    const float* Wout = (const float*)d_in[iwo];
    const float* bout = (const float*)d_in[ibo];
    float* out = (float*)d_out;

    char* ws = (char*)d_ws;
    float*          h0    = (float*)(ws + OFF_H0);
    float*          h1    = (float*)(ws + OFF_H1);
    unsigned short* hh    = (unsigned short*)(ws + OFF_HH);
    float*          Spart = (float*)(ws + OFF_SPART);
    float*          ssrc  = (float*)(ws + OFF_SSRC);
    float*          sdst  = (float*)(ws + OFF_SDST);
    float*          S     = (float*)(ws + OFF_S);
    unsigned short* WinT  = (unsigned short*)(ws + OFF_WINT);
    unsigned short* WgT   = (unsigned short*)(ws + OFF_WGT);
    unsigned short* WoutT = (unsigned short*)(ws + OFF_WOUTT);
    unsigned*       bm    = (unsigned*)(ws + OFF_BM);

    // ---- adjacency bitmap + weight convert/transpose, once ----
    hipMemsetAsync(bm, 0, BM_BYTES, stream);
    edge_bitmap<<<NEDGES/256, 256, 0, stream>>>(ei, bm);
    {
        dim3 g(192, 10);
        convert_weights<<<g, 256, 0, stream>>>(Win, Wg, Wout, WinT, WgT, WoutT);
    }

    // ---- input projection: h0 = relu(x @ Win + bin) ----
    {
        dim3 g(D_H/64, NNODES/32);
        gemm_mfma<<<g, 256, 0, stream>>>(x, WinT, bin_, h0, nullptr,
                                         NNODES, D_H, D_IN, 1,
                                         nullptr, nullptr, nullptr, nullptr);
    }

    float* hin = h0;
    float* hcur = h1;
    for (int l = 0; l < 2; ++l) {
        // hh = hin @ Wg[l] (bf16 out, + fused scores & column partial sums)
        dim3 g2(D_H/64, NNODES/32);
        gemm_mfma<<<g2, 256, 0, stream>>>(hin, WgT + (size_t)l*NHEAD*D_HEAD*D_H,
                                          nullptr, nullptr, hh,
                                          NNODES, D_H, D_H, 0,
                                          a + (size_t)l*NHEAD*128, ssrc, sdst, Spart);
        colsum2<<<1, 256, 0, stream>>>(Spart, S);
        aggregate_kernel<<<NNODES, 256, 0, stream>>>(bm, ssrc, sdst, hh, S, hcur);
        float* t = hin; hin = hcur; hcur = t;
    }

    // ---- output projection -> f32 ----
    {
        dim3 g(D_OUT/64, NNODES/32);
        gemm_mfma<<<g, 256, 0, stream>>>(hin, WoutT, bout, out, nullptr,
                                         NNODES, D_OUT, D_H, 0,
                                         nullptr, nullptr, nullptr, nullptr);
    }
}

// Round 9
// 87.958 us; speedup vs baseline: 3.9672x; 1.0897x over previous
//
#include <hip/hip_runtime.h>
#include <hip/hip_bf16.h>

#define NNODES 4096
#define NEDGES 131072
#define D_IN   768
#define D_H    256
#define NHEAD  4
#define D_HEAD 64
#define D_OUT  128
#define DEGCAP 192

typedef __attribute__((ext_vector_type(4))) float f32x4;
typedef __attribute__((ext_vector_type(8))) short bf16x8;
typedef __attribute__((ext_vector_type(8))) unsigned short u16x8;

static __device__ __forceinline__ unsigned short f2bf(float f) {
    __hip_bfloat16 h = __float2bfloat16(f);
    return *reinterpret_cast<unsigned short*>(&h);
}
static __device__ __forceinline__ float bf2f(unsigned short u) {
    return __uint_as_float((unsigned)u << 16);
}

// ---------------- workspace layout (bytes) ----------------
#define OFF_H0     (0u)                          // 4096*256*4 = 4MB (f32)
#define OFF_H1     (4u<<20)                      // 4MB (f32)
#define OFF_HH     (8u<<20)                      // 4096*256*2 = 2MB (bf16)
#define OFF_SPART  (10u<<20)                     // 128*256*4 = 131072
#define OFF_SSRC   (OFF_SPART + 131072u)         // 65536
#define OFF_SDST   (OFF_SSRC + 65536u)           // 65536
#define OFF_S      (OFF_SDST + 65536u)           // 1024
#define OFF_WINT   (OFF_S + 1024u)               // 256*768*2 = 393216
#define OFF_WGT    (OFF_WINT + 393216u)          // 8*64*256*2 = 262144
#define OFF_WOUTT  (OFF_WGT + 262144u)           // 128*256*2 = 65536
#define OFF_BM     (OFF_WOUTT + 65536u)          // 2MB
#define BM_BYTES   ((size_t)NNODES*128u*4u)

// ---------------- bitmap zero (rocclr fillBuffer was 40us latency-bound) ----------------
__global__ __launch_bounds__(256) void zero_bm(uint4* __restrict__ bm4)
{
    bm4[blockIdx.x*256 + threadIdx.x] = make_uint4(0u,0u,0u,0u);
}

// ---------------- adjacency bitmap (fused dtype autodetect; idempotent) ----------------
__global__ void edge_bitmap(const int* __restrict__ ei, unsigned* __restrict__ bm)
{
    __shared__ int is64_sh;
    int tid = threadIdx.x;
    if (tid < 64) {
        int v = ei[2*tid + 1];
        unsigned long long ball = __ballot(v == 0);
        if (tid == 0) is64_sh = (ball == ~0ull) ? 1 : 0;
    }
    __syncthreads();
    int is64 = is64_sh;
    int k = blockIdx.x*256 + tid;
    if (k >= NEDGES) return;
    int r = is64 ? ei[2*k]            : ei[k];
    int c = is64 ? ei[2*NEDGES + 2*k] : ei[NEDGES + k];
    r &= (NNODES-1); c &= (NNODES-1);
    atomicOr(&bm[(size_t)r*128 + (c>>5)], 1u << (c & 31));
}

// ---------------- weight transpose + f32->bf16 convert (once per call) ----------------
// mat 0: Win (768x256) -> WinT[256][768]; mats 1..8: Wg[lh] (256x64) -> WgT[lh][64][256];
// mat 9: Wout (256x128) -> WoutT[128][256].
__global__ __launch_bounds__(256) void convert_weights(
    const float* __restrict__ Win, const float* __restrict__ Wg,
    const float* __restrict__ Wout,
    unsigned short* __restrict__ WinT, unsigned short* __restrict__ WgT,
    unsigned short* __restrict__ WoutT)
{
    __shared__ float tile[32][33];
    int mat = blockIdx.y;
    const float* src; unsigned short* dst; int R, Cc;
    if (mat == 0)      { src = Win;                 dst = WinT;                 R = 768; Cc = 256; }
    else if (mat <= 8) { src = Wg + (size_t)(mat-1)*256*64; dst = WgT + (size_t)(mat-1)*64*256; R = 256; Cc = 64; }
    else               { src = Wout;                dst = WoutT;                R = 256; Cc = 128; }
    int tilesC = Cc >> 5;
    int tr = blockIdx.x / tilesC, tc = blockIdx.x % tilesC;
    if (tr*32 >= R) return;
    int ci = threadIdx.x & 31, rq = threadIdx.x >> 5;
    #pragma unroll
    for (int rr = rq; rr < 32; rr += 8)
        tile[rr][ci] = src[(size_t)(tr*32+rr)*Cc + tc*32 + ci];
    __syncthreads();
    int ri = threadIdx.x & 31, cq = threadIdx.x >> 5;
    #pragma unroll
    for (int cc = cq; cc < 32; cc += 8)
        dst[(size_t)(tc*32+cc)*R + tr*32 + ri] = f2bf(tile[ri][cc]);
}

// ---------------- MFMA GEMM: C = act(A@B + bias) ----------------
// A: MxK f32 (bf16-converted during staging). BT: NxK bf16 (pre-transposed).
// 32x64 tile, BK=64, 256 thr = 4 waves (wave = 16-col strip), 4 MFMA/wave/iter.
// Frags: lane holds free-idx=lane&15, k=(lane>>4)*8+i (per k-half);
// D: row=(lane>>4)*4+i (+16*t), col=lane&15.
// a_l != null (hh GEMM): epilogue computes ssrc/sdst + Spart col sums, C->bf16.
__global__ __launch_bounds__(256) void gemm_mfma(
    const float* __restrict__ A, const unsigned short* __restrict__ BT,
    const float* __restrict__ bias, float* __restrict__ Cf,
    unsigned short* __restrict__ Cb,
    int M, int N, int K, int relu,
    const float* __restrict__ a_l, float* __restrict__ ssrc,
    float* __restrict__ sdst, float* __restrict__ Spart)
{
    __shared__ unsigned short As[32][72];   // [row][k] bf16, 144B stride (2-way banks: free)
    __shared__ unsigned short Bs[64][72];   // [col][k] bf16
    __shared__ float sredS[4][32], sredD[4][32];
    const int tid = threadIdx.x;
    const int bx = blockIdx.x, by = blockIdx.y;
    const int wc = tid >> 6;                 // wave id = column strip
    const int lane = tid & 63;
    const int g = lane >> 4, c = lane & 15;
    const int ar = tid >> 3, ak = (tid & 7) * 8;   // A stage: 32r x (8thr x 8 f32)
    const int bc = tid >> 2, bk = (tid & 3) * 16;  // B stage: 64c x (4thr x 16 u16)
    f32x4 acc0 = {0.f,0.f,0.f,0.f}, acc1 = {0.f,0.f,0.f,0.f};
    const float* Arow = A + (size_t)(by*32 + ar)*K;
    const unsigned short* Brow = BT + (size_t)(bx*64 + bc)*K;

    for (int k0 = 0; k0 < K; k0 += 64) {
        float4 av0 = *(const float4*)&Arow[k0 + ak];
        float4 av1 = *(const float4*)&Arow[k0 + ak + 4];
        u16x8 bv0 = *(const u16x8*)&Brow[k0 + bk];
        u16x8 bv1 = *(const u16x8*)&Brow[k0 + bk + 8];
        ushort4 aw0, aw1;
        aw0.x = f2bf(av0.x); aw0.y = f2bf(av0.y); aw0.z = f2bf(av0.z); aw0.w = f2bf(av0.w);
        aw1.x = f2bf(av1.x); aw1.y = f2bf(av1.y); aw1.z = f2bf(av1.z); aw1.w = f2bf(av1.w);
        *(ushort4*)&As[ar][ak]     = aw0;
        *(ushort4*)&As[ar][ak + 4] = aw1;
        *(u16x8*)&Bs[bc][bk]     = bv0;
        *(u16x8*)&Bs[bc][bk + 8] = bv1;
        __syncthreads();
        bf16x8 b0  = *(bf16x8*)&Bs[wc*16 + c][g*8];
        bf16x8 b1  = *(bf16x8*)&Bs[wc*16 + c][32 + g*8];
        bf16x8 a00 = *(bf16x8*)&As[c][g*8];
        bf16x8 a01 = *(bf16x8*)&As[c][32 + g*8];
        bf16x8 a10 = *(bf16x8*)&As[16 + c][g*8];
        bf16x8 a11 = *(bf16x8*)&As[16 + c][32 + g*8];
        acc0 = __builtin_amdgcn_mfma_f32_16x16x32_bf16(a00, b0, acc0, 0, 0, 0);
        acc0 = __builtin_amdgcn_mfma_f32_16x16x32_bf16(a01, b1, acc0, 0, 0, 0);
        acc1 = __builtin_amdgcn_mfma_f32_16x16x32_bf16(a10, b0, acc1, 0, 0, 0);
        acc1 = __builtin_amdgcn_mfma_f32_16x16x32_bf16(a11, b1, acc1, 0, 0, 0);
        __syncthreads();
    }

    // ---- C store ----
    const int col = bx*64 + wc*16 + c;
    float bb = bias ? bias[col] : 0.f;
    #pragma unroll
    for (int t = 0; t < 2; ++t) {
        f32x4 av = t ? acc1 : acc0;
        #pragma unroll
        for (int i = 0; i < 4; ++i) {
            int r = by*32 + t*16 + g*4 + i;
            float v = av[i] + bb;
            if (relu) v = fmaxf(v, 0.f);
            if (Cb) Cb[(size_t)r*N + col] = f2bf(v);
            else    Cf[(size_t)r*N + col] = v;
        }
    }

    // ---- fused epilogue: attention scores + column partial sums ----
    if (a_l) {
        int h = bx;
        float as = a_l[h*128 + wc*16 + c];
        float ad = a_l[h*128 + 64 + wc*16 + c];
        float ps[8], pd[8], cs = 0.f;
        #pragma unroll
        for (int t = 0; t < 2; ++t) {
            f32x4 av = t ? acc1 : acc0;
            #pragma unroll
            for (int i = 0; i < 4; ++i) {
                ps[t*4+i] = av[i] * as;
                pd[t*4+i] = av[i] * ad;
                cs += av[i];
            }
        }
        #pragma unroll
        for (int off = 1; off < 16; off <<= 1) {
            #pragma unroll
            for (int j = 0; j < 8; ++j) {
                ps[j] += __shfl_xor(ps[j], off);
                pd[j] += __shfl_xor(pd[j], off);
            }
        }
        if (c == 0) {
            #pragma unroll
            for (int t = 0; t < 2; ++t)
                #pragma unroll
                for (int i = 0; i < 4; ++i) {
                    sredS[wc][t*16 + g*4 + i] = ps[t*4+i];
                    sredD[wc][t*16 + g*4 + i] = pd[t*4+i];
                }
        }
        // column sums over the 32 rows: reduce across g-groups
        cs += __shfl_xor(cs, 16);
        cs += __shfl_xor(cs, 32);
        if (g == 0)
            Spart[by*256 + h*64 + wc*16 + c] = cs;
        __syncthreads();
        if (tid < 32) {
            float s1 = sredS[0][tid] + sredS[1][tid] + sredS[2][tid] + sredS[3][tid];
            float s2 = sredD[0][tid] + sredD[1][tid] + sredD[2][tid] + sredD[3][tid];
            int r = by*32 + tid;
            ssrc[r*4 + h] = s1;
            sdst[r*4 + h] = s2;
        }
    }
}

// ---------------- colsum stage 2: S[c] = sum_by Spart[by][c] ----------------
__global__ void colsum2(const float* __restrict__ Spart, float* __restrict__ S)
{
    int j = threadIdx.x;
    float s = 0.f;
    for (int b = 0; b < 128; ++b) s += Spart[b*256 + j];
    S[j] = s;                     // deterministic
}

// ---------------- per-node aggregation + dense-softmax + relu ----------------
// Neighbor list built in-kernel from the bitmap row. Exact dense-softmax identity:
//   M = max(0, max_e e); base = exp(-M)
//   Z = sum_edges(exp(e-M)-base) + N*base
//   hp = [ sum_edges (exp(e-M)-base)*hh[m] + base*S ] / Z
__global__ __launch_bounds__(256) void aggregate_kernel(
    const unsigned* __restrict__ bm,
    const float* __restrict__ ssrc, const float* __restrict__ sdst,
    const unsigned short* __restrict__ hh, const float* __restrict__ S,
    float* __restrict__ hout)
{
    __shared__ int   csr_lds[DEGCAP];
    __shared__ float w_lds[4*DEGCAP];
    __shared__ int   cnt_sh;
    int n = blockIdx.x;
    int tid = threadIdx.x;
    int h = tid >> 6, o = tid & 63;
    const unsigned* brow = bm + (size_t)n*128;

    if (tid < 64) {
        unsigned wA = brow[2*tid], wB = brow[2*tid + 1];
        int cpc = __popc(wA) + __popc(wB);
        int pre = cpc;
        #pragma unroll
        for (int off = 1; off < 64; off <<= 1) {
            int v = __shfl_up(pre, off);
            if (tid >= off) pre += v;
        }
        int excl = pre - cpc;
        int total = __shfl(pre, 63);
        if (total <= DEGCAP) {
            int pos = excl, base = tid*64;
            unsigned w = wA;
            while (w) { int b = __builtin_ctz(w); csr_lds[pos++] = base + b; w &= w-1; }
            w = wB; base += 32;
            while (w) { int b = __builtin_ctz(w); csr_lds[pos++] = base + b; w &= w-1; }
        }
        if (tid == 0) cnt_sh = total;
    }
    __syncthreads();
    int cnt = cnt_sh;
    float ss = ssrc[n*4 + h];

    if (cnt <= DEGCAP) {
        float mx = 0.f;
        for (int i = o; i < cnt; i += 64) {
            int m = csr_lds[i];
            float e = ss + sdst[m*4 + h];
            e = (e >= 0.f) ? e : 0.2f*e;
            mx = fmaxf(mx, e);
        }
        #pragma unroll
        for (int off = 32; off; off >>= 1) mx = fmaxf(mx, __shfl_xor(mx, off));
        float M = mx;
        float base = expf(-M);

        float zp = 0.f;
        for (int i = o; i < cnt; i += 64) {
            int m = csr_lds[i];
            float e = ss + sdst[m*4 + h];
            e = (e >= 0.f) ? e : 0.2f*e;
            float w = expf(e - M) - base;
            w_lds[h*DEGCAP + i] = w;
            zp += w;
        }
        #pragma unroll
        for (int off = 32; off; off >>= 1) zp += __shfl_xor(zp, off);

        float acc = 0.f;
        int i = 0;
        for (; i + 4 <= cnt; i += 4) {
            int m0 = csr_lds[i],   m1 = csr_lds[i+1];
            int m2 = csr_lds[i+2], m3 = csr_lds[i+3];
            float w0 = w_lds[h*DEGCAP+i],   w1 = w_lds[h*DEGCAP+i+1];
            float w2 = w_lds[h*DEGCAP+i+2], w3 = w_lds[h*DEGCAP+i+3];
            float v0 = bf2f(hh[(size_t)m0*256 + h*64 + o]);
            float v1 = bf2f(hh[(size_t)m1*256 + h*64 + o]);
            float v2 = bf2f(hh[(size_t)m2*256 + h*64 + o]);
            float v3 = bf2f(hh[(size_t)m3*256 + h*64 + o]);
            acc += w0*v0; acc += w1*v1; acc += w2*v2; acc += w3*v3;
        }
        for (; i < cnt; ++i)
            acc += w_lds[h*DEGCAP+i] * bf2f(hh[(size_t)csr_lds[i]*256 + h*64 + o]);

        float Z  = zp + (float)NNODES * base;
        float hp = (acc + base * S[h*64 + o]) / Z;
        hout[(size_t)n*256 + h*64 + o] = fmaxf(hp, 0.f);
    } else {
        float mx = 0.f;
        for (int m = o; m < NNODES; m += 64) {
            if ((brow[m>>5] >> (m & 31)) & 1u) {
                float e = ss + sdst[m*4 + h];
                e = (e >= 0.f) ? e : 0.2f*e;
                mx = fmaxf(mx, e);
            }
        }
        #pragma unroll
        for (int off = 32; off; off >>= 1) mx = fmaxf(mx, __shfl_xor(mx, off));
        float M = mx;
        float base = expf(-M);
        float zp = 0.f, acc = 0.f;
        for (int m = 0; m < NNODES; ++m) {
            if ((brow[m>>5] >> (m & 31)) & 1u) {
                float e = ss + sdst[m*4 + h];
                e = (e >= 0.f) ? e : 0.2f*e;
                float w = expf(e - M) - base;
                zp += w;
                acc += w * bf2f(hh[(size_t)m*256 + h*64 + o]);
            }
        }
        float Z  = zp + (float)NNODES * base;
        float hp = (acc + base * S[h*64 + o]) / Z;
        hout[(size_t)n*256 + h*64 + o] = fmaxf(hp, 0.f);
    }
}

// ---------------- host: size-based input resolution ----------------
static int find_size(const int* sz, int n, int want, int fallback)
{
    for (int i = 0; i < n; ++i) if (sz[i] == want) return i;
    return fallback;
}

extern "C" void kernel_launch(void* const* d_in, const int* in_sizes, int n_in,
                              void* d_out, int out_size, void* d_ws, size_t ws_size,
                              hipStream_t stream)
{
    int ix   = find_size(in_sizes, n_in, NNODES*D_IN, 0);          // 3145728
    int ie   = find_size(in_sizes, n_in, 2*NEDGES, 1);             // 262144
    int iwin = find_size(in_sizes, n_in, D_IN*D_H, 2);             // 196608
    int ibin = find_size(in_sizes, n_in, D_H, 3);                  // 256
    int iwg  = find_size(in_sizes, n_in, 2*NHEAD*D_H*D_HEAD, 4);   // 131072
    int ia   = find_size(in_sizes, n_in, 2*NHEAD*2*D_HEAD, 5);     // 1024
    int iwo  = find_size(in_sizes, n_in, D_H*D_OUT, 6);            // 32768
    int ibo  = find_size(in_sizes, n_in, D_OUT, 7);                // 128

    const float* x    = (const float*)d_in[ix];
    const int*   ei   = (const int*)d_in[ie];
    const float* Win  = (const float*)d_in[iwin];
    const float* bin_ = (const float*)d_in[ibin];
    const float* Wg   = (const float*)d_in[iwg];
    const float* a    = (const float*)d_in[ia];
    const float* Wout = (const float*)d_in[iwo];
    const float* bout = (const float*)d_in[ibo];
    float* out = (float*)d_out;

    char* ws = (char*)d_ws;
    float*          h0    = (float*)(ws + OFF_H0);
    float*          h1    = (float*)(ws + OFF_H1);
    unsigned short* hh    = (unsigned short*)(ws + OFF_HH);
    float*          Spart = (float*)(ws + OFF_SPART);
    float*          ssrc  = (float*)(ws + OFF_SSRC);
    float*          sdst  = (float*)(ws + OFF_SDST);
    float*          S     = (float*)(ws + OFF_S);
    unsigned short* WinT  = (unsigned short*)(ws + OFF_WINT);
    unsigned short* WgT   = (unsigned short*)(ws + OFF_WGT);
    unsigned short* WoutT = (unsigned short*)(ws + OFF_WOUTT);
    unsigned*       bm    = (unsigned*)(ws + OFF_BM);

    // ---- bitmap zero + build + weight convert, once (layer-invariant) ----
    zero_bm<<<512, 256, 0, stream>>>((uint4*)bm);
    edge_bitmap<<<NEDGES/256, 256, 0, stream>>>(ei, bm);
    {
        dim3 g(192, 10);
        convert_weights<<<g, 256, 0, stream>>>(Win, Wg, Wout, WinT, WgT, WoutT);
    }

    // ---- input projection: h0 = relu(x @ Win + bin) ----
    {
        dim3 g(D_H/64, NNODES/32);
        gemm_mfma<<<g, 256, 0, stream>>>(x, WinT, bin_, h0, nullptr,
                                         NNODES, D_H, D_IN, 1,
                                         nullptr, nullptr, nullptr, nullptr);
    }

    float* hin = h0;
    float* hcur = h1;
    for (int l = 0; l < 2; ++l) {
        // hh = hin @ Wg[l] (bf16 out, + fused scores & column partial sums)
        dim3 g2(D_H/64, NNODES/32);
        gemm_mfma<<<g2, 256, 0, stream>>>(hin, WgT + (size_t)l*NHEAD*D_HEAD*D_H,
                                          nullptr, nullptr, hh,
                                          NNODES, D_H, D_H, 0,
                                          a + (size_t)l*NHEAD*128, ssrc, sdst, Spart);
        colsum2<<<1, 256, 0, stream>>>(Spart, S);
        aggregate_kernel<<<NNODES, 256, 0, stream>>>(bm, ssrc, sdst, hh, S, hcur);
        float* t = hin; hin = hcur; hcur = t;
    }

    // ---- output projection -> f32 ----
    {
        dim3 g(D_OUT/64, NNODES/32);
        gemm_mfma<<<g, 256, 0, stream>>>(hin, WoutT, bout, out, nullptr,
                                         NNODES, D_OUT, D_H, 0,
                                         nullptr, nullptr, nullptr, nullptr);
    }
}